// Round 2
// baseline (354.222 us; speedup 1.0000x reference)
//
#include <hip/hip_runtime.h>

typedef __attribute__((ext_vector_type(8))) short bf16x8;
typedef __attribute__((ext_vector_type(4))) float f32x4;

#define NH 12
#define DHD 64
#define NB 8
#define NSEQ 1024
#define DMODEL 768
#define BHN (NB*NH)            // 96
#define ROWS_PER (BHN*NSEQ)    // 98304

#define MFMA(a,b,c) __builtin_amdgcn_mfma_f32_16x16x32_bf16(a,b,c,0,0,0)

__device__ __forceinline__ unsigned short f2bf(float f) {
  unsigned int u = __float_as_uint(f);
  u += 0x7FFFu + ((u >> 16) & 1u);
  return (unsigned short)(u >> 16);
}
__device__ __forceinline__ float bf2f(unsigned short s) {
  return __uint_as_float(((unsigned int)s) << 16);
}

__device__ __forceinline__ void gload16(const void* g, void* l) {
  __builtin_amdgcn_global_load_lds(
      (__attribute__((address_space(1))) void*)(g),
      (__attribute__((address_space(3))) void*)(l), 16, 0, 0);
}

__global__ __launch_bounds__(256) void cast_kernel(const float* __restrict__ in,
                                                   unsigned short* __restrict__ out, int n) {
  int i = (blockIdx.x * blockDim.x + threadIdx.x) * 4;
  if (i < n) {
    float4 v = *(const float4*)(in + i);
    ushort4 o;
    o.x = f2bf(v.x); o.y = f2bf(v.y); o.z = f2bf(v.z); o.w = f2bf(v.w);
    *(ushort4*)(out + i) = o;
  }
}

// split fp32 into hi bf16 + lo bf16 (residual)
__global__ __launch_bounds__(256) void cast_split_kernel(const float* __restrict__ in,
                                                         unsigned short* __restrict__ hi,
                                                         unsigned short* __restrict__ lo, int n) {
  int i = (blockIdx.x * blockDim.x + threadIdx.x) * 4;
  if (i < n) {
    float4 v = *(const float4*)(in + i);
    float vv[4] = {v.x, v.y, v.z, v.w};
    ushort4 h, l;
    unsigned short hs[4], ls[4];
#pragma unroll
    for (int e = 0; e < 4; e++) {
      hs[e] = f2bf(vv[e]);
      ls[e] = f2bf(vv[e] - bf2f(hs[e]));
    }
    h.x = hs[0]; h.y = hs[1]; h.z = hs[2]; h.w = hs[3];
    l.x = ls[0]; l.y = ls[1]; l.z = ls[2]; l.w = ls[3];
    *(ushort4*)(hi + i) = h;
    *(ushort4*)(lo + i) = l;
  }
}

// C = A(MxK) * B(NxK)^T
// MODE 0: plain bf16 inputs (Ah,Bh), fp32 row-major C (M x N)
// MODE 1: split inputs (Ah+Al, Bh+Bl), fp32 store remapped to [qkv][b*H+h][nseq][64]
template<int MODE>
__global__ __launch_bounds__(256) void gemm_bt(const unsigned short* __restrict__ Ah,
                                               const unsigned short* __restrict__ Al,
                                               const unsigned short* __restrict__ Bh,
                                               const unsigned short* __restrict__ Bl,
                                               float* __restrict__ Cout,
                                               int M, int N, int K) {
  __shared__ __align__(16) unsigned short Ash[(MODE ? 2 : 1) * 128 * 32];
  __shared__ __align__(16) unsigned short Bsh[(MODE ? 2 : 1) * 128 * 32];
  const int tid = threadIdx.x;
  const int w = tid >> 6, l = tid & 63;
  const int wr = w >> 1, wc = w & 1;
  const int g = l >> 4, i16 = l & 15;
  const int bx = blockIdx.x, by = blockIdx.y;

  const f32x4 fzero = {0.f, 0.f, 0.f, 0.f};
  f32x4 acc[4][4];
#pragma unroll
  for (int i = 0; i < 4; i++)
#pragma unroll
    for (int j = 0; j < 4; j++) acc[i][j] = fzero;

  const size_t arow = (size_t)(by*128 + (tid >> 2))*K + (tid & 3)*8;
  const size_t brow = (size_t)(bx*128 + (tid >> 2))*K + (tid & 3)*8;
  char* AlB = (char*)Ash + w*1024;
  char* BlB = (char*)Bsh + w*1024;

  for (int k0 = 0; k0 < K; k0 += 32) {
    __syncthreads();
    gload16(Ah + arow + k0, AlB);
    gload16(Ah + arow + (size_t)64*K + k0, AlB + 4096);
    gload16(Bh + brow + k0, BlB);
    gload16(Bh + brow + (size_t)64*K + k0, BlB + 4096);
    if (MODE == 1) {
      gload16(Al + arow + k0, AlB + 8192);
      gload16(Al + arow + (size_t)64*K + k0, AlB + 8192 + 4096);
      gload16(Bl + brow + k0, BlB + 8192);
      gload16(Bl + brow + (size_t)64*K + k0, BlB + 8192 + 4096);
    }
    __syncthreads();
    bf16x8 afh[4], bfh[4];
#pragma unroll
    for (int i = 0; i < 4; i++)
      afh[i] = *(const bf16x8*)(Ash + (wr*64 + i*16 + i16)*32 + g*8);
#pragma unroll
    for (int j = 0; j < 4; j++)
      bfh[j] = *(const bf16x8*)(Bsh + (wc*64 + j*16 + i16)*32 + g*8);
    if (MODE == 1) {
      bf16x8 afl[4], bfl[4];
#pragma unroll
      for (int i = 0; i < 4; i++)
        afl[i] = *(const bf16x8*)(Ash + 4096 + (wr*64 + i*16 + i16)*32 + g*8);
#pragma unroll
      for (int j = 0; j < 4; j++)
        bfl[j] = *(const bf16x8*)(Bsh + 4096 + (wc*64 + j*16 + i16)*32 + g*8);
#pragma unroll
      for (int i = 0; i < 4; i++)
#pragma unroll
        for (int j = 0; j < 4; j++) {
          acc[i][j] = MFMA(afh[i], bfh[j], acc[i][j]);
          acc[i][j] = MFMA(afh[i], bfl[j], acc[i][j]);
          acc[i][j] = MFMA(afl[i], bfh[j], acc[i][j]);
        }
    } else {
#pragma unroll
      for (int i = 0; i < 4; i++)
#pragma unroll
        for (int j = 0; j < 4; j++)
          acc[i][j] = MFMA(afh[i], bfh[j], acc[i][j]);
    }
  }

  const int m0 = by*128 + wr*64;
  const int n0 = bx*128 + wc*64;
  if (MODE == 0) {
#pragma unroll
    for (int i = 0; i < 4; i++)
#pragma unroll
      for (int j = 0; j < 4; j++)
#pragma unroll
        for (int r = 0; r < 4; r++) {
          int m = m0 + i*16 + g*4 + r;
          int n = n0 + j*16 + i16;
          Cout[(size_t)m*N + n] = acc[i][j][r];
        }
  } else {
#pragma unroll
    for (int j = 0; j < 4; j++) {
      int n = n0 + j*16 + i16;
      int qkv = n / DMODEL;
      int rem = n - qkv*DMODEL;
      int h = rem >> 6, dh = rem & 63;
#pragma unroll
      for (int i = 0; i < 4; i++)
#pragma unroll
        for (int r = 0; r < 4; r++) {
          int m = m0 + i*16 + g*4 + r;
          int b = m >> 10, ns = m & 1023;
          size_t dst = (((size_t)qkv*BHN + b*NH + h)*NSEQ + ns)*DHD + dh;
          Cout[dst] = acc[i][j][r];
        }
    }
  }
}

// in-place fp32 rms-norm (+scale) + 2D RoPE on QKV [qkv][bh][n][64]
__global__ __launch_bounds__(256) void normrope_kernel(float* __restrict__ QKV,
                                                       const int* __restrict__ pos_ids,
                                                       const float* __restrict__ q_scale,
                                                       const float* __restrict__ k_scale) {
  const int w = threadIdx.x >> 6, l = threadIdx.x & 63;
  const int row = blockIdx.x * 4 + w;                 // 0 .. 294911
  const int qkv = row / ROWS_PER;
  const int rem = row - qkv*ROWS_PER;
  const int bh = rem >> 10, ns = rem & 1023;
  const int b = bh / NH;
  const size_t off = (size_t)row * DHD + l;
  float x = QKV[off];
  float ss = x * x;
#pragma unroll
  for (int d = 1; d < 64; d <<= 1) ss += __shfl_xor(ss, d);
  float xn = x * rsqrtf(ss * (1.0f/64.0f) + 1e-6f);
  if (qkv == 0) xn *= q_scale[l];
  else if (qkv == 1) xn *= k_scale[l];
  if (qkv < 2) {
    int p = l >> 5, t = l & 31, idx = t & 15;
    float pos = (float)pos_ids[(b*NSEQ + ns)*2 + p];
    // inv = 100^(-idx/16) = exp(-idx*ln(100)/16)
    float ang = pos * __expf((float)idx * (-4.605170185988091f / 16.0f));
    float sn, cs;
    __sincosf(ang, &sn, &cs);
    float partner = __shfl_xor(xn, 16);
    xn = (t < 16) ? (xn*cs - partner*sn) : (xn*cs + partner*sn);
  }
  QKV[off] = xn;
}

// flash attention: grid (16 qblocks, 96 bh), 4 waves x 16 q rows, KV tile = 32
// fp32 Q/K/V input; QK^T via split hi/lo bf16 (3-term), PV in plain bf16.
__global__ __launch_bounds__(256) void attn_kernel(const float* __restrict__ QKVf,
                                                   unsigned short* __restrict__ O) {
  const int bh = blockIdx.y;
  const int q0 = blockIdx.x * 64;
  const int tid = threadIdx.x, w = tid >> 6, l = tid & 63;
  const int g = l >> 4, i16 = l & 15;
  const int b = bh / NH, h = bh - b*NH;

  const float* Qp = QKVf + (size_t)bh*NSEQ*DHD;
  const float* Kp = QKVf + ((size_t)BHN + bh)*NSEQ*DHD;
  const float* Vp = QKVf + ((size_t)2*BHN + bh)*NSEQ*DHD;

  __shared__ __align__(16) unsigned short Klh[32*72];
  __shared__ __align__(16) unsigned short Kll[32*72];
  __shared__ __align__(16) unsigned short Vt[64*40];
  __shared__ __align__(16) unsigned short Pl[4][16*40];

  // Q fragments hi/lo (rows q0 + w*16 + i16, d chunks g*8 and 32+g*8)
  bf16x8 qh0, ql0, qh1, ql1;
  {
    const float* qrow = Qp + (size_t)(q0 + w*16 + i16)*DHD + g*8;
    float4 a0 = *(const float4*)(qrow);
    float4 a1 = *(const float4*)(qrow + 4);
    float4 b0 = *(const float4*)(qrow + 32);
    float4 b1 = *(const float4*)(qrow + 36);
    float c0[8] = {a0.x,a0.y,a0.z,a0.w,a1.x,a1.y,a1.z,a1.w};
    float c1[8] = {b0.x,b0.y,b0.z,b0.w,b1.x,b1.y,b1.z,b1.w};
#pragma unroll
    for (int e = 0; e < 8; e++) {
      unsigned short hh = f2bf(c0[e]);
      qh0[e] = (short)hh; ql0[e] = (short)f2bf(c0[e] - bf2f(hh));
      unsigned short h2 = f2bf(c1[e]);
      qh1[e] = (short)h2; ql1[e] = (short)f2bf(c1[e] - bf2f(h2));
    }
  }

  const f32x4 fzero = {0.f, 0.f, 0.f, 0.f};
  float mR[4], lR[4];
  f32x4 o[4];
#pragma unroll
  for (int r = 0; r < 4; r++) { mR[r] = -1e30f; lR[r] = 0.f; }
#pragma unroll
  for (int t = 0; t < 4; t++) o[t] = fzero;

  const int krow = tid >> 3, kcol = (tid & 7) * 8;
  const int vkv = tid & 31, vdh = (tid >> 5) * 8;

  for (int kv0 = 0; kv0 < NSEQ; kv0 += 32) {
    __syncthreads();
    {
      const float* kr = Kp + (size_t)(kv0 + krow)*DHD + kcol;
      float4 ka = *(const float4*)(kr);
      float4 kb = *(const float4*)(kr + 4);
      float kk[8] = {ka.x,ka.y,ka.z,ka.w,kb.x,kb.y,kb.z,kb.w};
      bf16x8 vh, vl;
#pragma unroll
      for (int e = 0; e < 8; e++) {
        unsigned short hh = f2bf(kk[e]);
        vh[e] = (short)hh;
        vl[e] = (short)f2bf(kk[e] - bf2f(hh));
      }
      *(bf16x8*)(Klh + krow*72 + kcol) = vh;
      *(bf16x8*)(Kll + krow*72 + kcol) = vl;
    }
    {
      const float* vr = Vp + (size_t)(kv0 + vkv)*DHD + vdh;
      float4 va = *(const float4*)(vr);
      float4 vb = *(const float4*)(vr + 4);
      float vvv[8] = {va.x,va.y,va.z,va.w,vb.x,vb.y,vb.z,vb.w};
#pragma unroll
      for (int jj = 0; jj < 8; jj++) Vt[(vdh + jj)*40 + vkv] = f2bf(vvv[jj]);
    }
    __syncthreads();

    f32x4 s0 = fzero, s1 = fzero;
    {
      bf16x8 kh00 = *(const bf16x8*)(Klh + i16*72 + g*8);
      bf16x8 kh01 = *(const bf16x8*)(Klh + i16*72 + 32 + g*8);
      bf16x8 kl00 = *(const bf16x8*)(Kll + i16*72 + g*8);
      bf16x8 kl01 = *(const bf16x8*)(Kll + i16*72 + 32 + g*8);
      s0 = MFMA(qh0, kh00, s0);
      s0 = MFMA(qh1, kh01, s0);
      s0 = MFMA(ql0, kh00, s0);
      s0 = MFMA(ql1, kh01, s0);
      s0 = MFMA(qh0, kl00, s0);
      s0 = MFMA(qh1, kl01, s0);
      bf16x8 kh10 = *(const bf16x8*)(Klh + (16 + i16)*72 + g*8);
      bf16x8 kh11 = *(const bf16x8*)(Klh + (16 + i16)*72 + 32 + g*8);
      bf16x8 kl10 = *(const bf16x8*)(Kll + (16 + i16)*72 + g*8);
      bf16x8 kl11 = *(const bf16x8*)(Kll + (16 + i16)*72 + 32 + g*8);
      s1 = MFMA(qh0, kh10, s1);
      s1 = MFMA(qh1, kh11, s1);
      s1 = MFMA(ql0, kh10, s1);
      s1 = MFMA(ql1, kh11, s1);
      s1 = MFMA(qh0, kl10, s1);
      s1 = MFMA(qh1, kl11, s1);
    }

    float fac[4];
#pragma unroll
    for (int r = 0; r < 4; r++) {
      float tm = fmaxf(s0[r], s1[r]);
#pragma unroll
      for (int d = 1; d < 16; d <<= 1) tm = fmaxf(tm, __shfl_xor(tm, d));
      float mn = fmaxf(mR[r], tm);
      fac[r] = __expf(mR[r] - mn);
      mR[r] = mn;
      float p0 = __expf(s0[r] - mn);
      float p1 = __expf(s1[r] - mn);
      s0[r] = p0; s1[r] = p1;
      float rs = p0 + p1;
#pragma unroll
      for (int d = 1; d < 16; d <<= 1) rs += __shfl_xor(rs, d);
      lR[r] = lR[r]*fac[r] + rs;
    }
#pragma unroll
    for (int r = 0; r < 4; r++) {
      Pl[w][(g*4 + r)*40 + i16]      = f2bf(s0[r]);
      Pl[w][(g*4 + r)*40 + 16 + i16] = f2bf(s1[r]);
    }
#pragma unroll
    for (int t = 0; t < 4; t++)
#pragma unroll
      for (int r = 0; r < 4; r++) o[t][r] *= fac[r];

    bf16x8 ap = *(const bf16x8*)(&Pl[w][i16*40 + g*8]);
#pragma unroll
    for (int t = 0; t < 4; t++) {
      bf16x8 bv = *(const bf16x8*)(Vt + (t*16 + i16)*40 + g*8);
      o[t] = MFMA(ap, bv, o[t]);
    }
  }

#pragma unroll
  for (int r = 0; r < 4; r++) {
    float invl = 1.0f / lR[r];
    int q = q0 + w*16 + g*4 + r;
    size_t base = ((size_t)(b*NSEQ + q))*DMODEL + h*DHD;
#pragma unroll
    for (int t = 0; t < 4; t++)
      O[base + t*16 + i16] = f2bf(o[t][r] * invl);
  }
}

extern "C" void kernel_launch(void* const* d_in, const int* in_sizes, int n_in,
                              void* d_out, int out_size, void* d_ws, size_t ws_size,
                              hipStream_t stream) {
  const float* hs = (const float*)d_in[0];
  const int*   pos = (const int*)d_in[1];
  const float* Wq = (const float*)d_in[2];
  const float* Wk = (const float*)d_in[3];
  const float* Wv = (const float*)d_in[4];
  const float* Wo = (const float*)d_in[5];
  const float* qs = (const float*)d_in[6];
  const float* ks = (const float*)d_in[7];

  const int nhs = 8192*768;       // 6291456
  const int nw  = 768*768;        // 589824

  char* p = (char*)d_ws;
  unsigned short* Xh  = (unsigned short*)p; p += (size_t)nhs*2;
  unsigned short* Xl  = (unsigned short*)p; p += (size_t)nhs*2;
  unsigned short* Wh  = (unsigned short*)p; p += (size_t)3*nw*2;
  unsigned short* Wl  = (unsigned short*)p; p += (size_t)3*nw*2;
  unsigned short* Wob = (unsigned short*)p; p += (size_t)nw*2;
  float*          QKVf= (float*)p;          p += (size_t)3*BHN*NSEQ*DHD*4;
  unsigned short* Ob  = Xh;  // alias: Xh dead after QKV GEMM

  cast_split_kernel<<<nhs/1024, 256, 0, stream>>>(hs, Xh, Xl, nhs);
  cast_split_kernel<<<nw/1024, 256, 0, stream>>>(Wq, Wh, Wl, nw);
  cast_split_kernel<<<nw/1024, 256, 0, stream>>>(Wk, Wh + nw, Wl + nw, nw);
  cast_split_kernel<<<nw/1024, 256, 0, stream>>>(Wv, Wh + 2*nw, Wl + 2*nw, nw);
  cast_kernel<<<nw/1024, 256, 0, stream>>>(Wo, Wob, nw);

  gemm_bt<1><<<dim3(18, 64), 256, 0, stream>>>(Xh, Xl, Wh, Wl, QKVf, 8192, 2304, 768);
  normrope_kernel<<<(3*ROWS_PER)/4, 256, 0, stream>>>(QKVf, pos, qs, ks);
  attn_kernel<<<dim3(16, 96), 256, 0, stream>>>(QKVf, Ob);
  gemm_bt<0><<<dim3(6, 64), 256, 0, stream>>>(Ob, nullptr, Wob, nullptr,
                                              (float*)d_out, 8192, 768, 768);
}

// Round 3
// 334.257 us; speedup vs baseline: 1.0597x; 1.0597x over previous
//
#include <hip/hip_runtime.h>

typedef __attribute__((ext_vector_type(8))) short bf16x8;
typedef __attribute__((ext_vector_type(4))) float f32x4;

#define NH 12
#define DHD 64
#define NB 8
#define NSEQ 1024
#define DMODEL 768
#define BHN (NB*NH)            // 96
#define ROWS_PER (BHN*NSEQ)    // 98304

#define MFMA(a,b,c) __builtin_amdgcn_mfma_f32_16x16x32_bf16(a,b,c,0,0,0)

__device__ __forceinline__ unsigned short f2bf(float f) {
  unsigned int u = __float_as_uint(f);
  u += 0x7FFFu + ((u >> 16) & 1u);
  return (unsigned short)(u >> 16);
}
__device__ __forceinline__ float bf2f(unsigned short s) {
  return __uint_as_float(((unsigned int)s) << 16);
}

__device__ __forceinline__ void gload16(const void* g, void* l) {
  __builtin_amdgcn_global_load_lds(
      (__attribute__((address_space(1))) void*)(g),
      (__attribute__((address_space(3))) void*)(l), 16, 0, 0);
}

__global__ __launch_bounds__(256) void cast_kernel(const float* __restrict__ in,
                                                   unsigned short* __restrict__ out, int n) {
  int i = (blockIdx.x * blockDim.x + threadIdx.x) * 4;
  if (i < n) {
    float4 v = *(const float4*)(in + i);
    ushort4 o;
    o.x = f2bf(v.x); o.y = f2bf(v.y); o.z = f2bf(v.z); o.w = f2bf(v.w);
    *(ushort4*)(out + i) = o;
  }
}

// split fp32 into hi bf16 + lo bf16 (residual)
__global__ __launch_bounds__(256) void cast_split_kernel(const float* __restrict__ in,
                                                         unsigned short* __restrict__ hi,
                                                         unsigned short* __restrict__ lo, int n) {
  int i = (blockIdx.x * blockDim.x + threadIdx.x) * 4;
  if (i < n) {
    float4 v = *(const float4*)(in + i);
    float vv[4] = {v.x, v.y, v.z, v.w};
    ushort4 h, l;
    unsigned short hs[4], ls[4];
#pragma unroll
    for (int e = 0; e < 4; e++) {
      hs[e] = f2bf(vv[e]);
      ls[e] = f2bf(vv[e] - bf2f(hs[e]));
    }
    h.x = hs[0]; h.y = hs[1]; h.z = hs[2]; h.w = hs[3];
    l.x = ls[0]; l.y = ls[1]; l.z = ls[2]; l.w = ls[3];
    *(ushort4*)(hi + i) = h;
    *(ushort4*)(lo + i) = l;
  }
}

// C = A(MxK) * B(NxK)^T
// MODE 0: plain bf16 inputs (Ah,Bh), fp32 row-major C (M x N)
// MODE 1: split inputs; Q,K -> fp32 remapped [qkv][bh][ns][64]; V -> bf16 Vout [bh][ns][64]
template<int MODE>
__global__ __launch_bounds__(256) void gemm_bt(const unsigned short* __restrict__ Ah,
                                               const unsigned short* __restrict__ Al,
                                               const unsigned short* __restrict__ Bh,
                                               const unsigned short* __restrict__ Bl,
                                               float* __restrict__ Cout,
                                               unsigned short* __restrict__ Vout,
                                               int M, int N, int K) {
  __shared__ __align__(16) unsigned short Ash[(MODE ? 2 : 1) * 128 * 32];
  __shared__ __align__(16) unsigned short Bsh[(MODE ? 2 : 1) * 128 * 32];
  const int tid = threadIdx.x;
  const int w = tid >> 6, l = tid & 63;
  const int wr = w >> 1, wc = w & 1;
  const int g = l >> 4, i16 = l & 15;
  const int bx = blockIdx.x, by = blockIdx.y;

  const f32x4 fzero = {0.f, 0.f, 0.f, 0.f};
  f32x4 acc[4][4];
#pragma unroll
  for (int i = 0; i < 4; i++)
#pragma unroll
    for (int j = 0; j < 4; j++) acc[i][j] = fzero;

  const size_t arow = (size_t)(by*128 + (tid >> 2))*K + (tid & 3)*8;
  const size_t brow = (size_t)(bx*128 + (tid >> 2))*K + (tid & 3)*8;
  char* AlB = (char*)Ash + w*1024;
  char* BlB = (char*)Bsh + w*1024;

  for (int k0 = 0; k0 < K; k0 += 32) {
    __syncthreads();
    gload16(Ah + arow + k0, AlB);
    gload16(Ah + arow + (size_t)64*K + k0, AlB + 4096);
    gload16(Bh + brow + k0, BlB);
    gload16(Bh + brow + (size_t)64*K + k0, BlB + 4096);
    if (MODE == 1) {
      gload16(Al + arow + k0, AlB + 8192);
      gload16(Al + arow + (size_t)64*K + k0, AlB + 8192 + 4096);
      gload16(Bl + brow + k0, BlB + 8192);
      gload16(Bl + brow + (size_t)64*K + k0, BlB + 8192 + 4096);
    }
    __syncthreads();
    bf16x8 afh[4], bfh[4];
#pragma unroll
    for (int i = 0; i < 4; i++)
      afh[i] = *(const bf16x8*)(Ash + (wr*64 + i*16 + i16)*32 + g*8);
#pragma unroll
    for (int j = 0; j < 4; j++)
      bfh[j] = *(const bf16x8*)(Bsh + (wc*64 + j*16 + i16)*32 + g*8);
    if (MODE == 1) {
      bf16x8 afl[4], bfl[4];
#pragma unroll
      for (int i = 0; i < 4; i++)
        afl[i] = *(const bf16x8*)(Ash + 4096 + (wr*64 + i*16 + i16)*32 + g*8);
#pragma unroll
      for (int j = 0; j < 4; j++)
        bfl[j] = *(const bf16x8*)(Bsh + 4096 + (wc*64 + j*16 + i16)*32 + g*8);
#pragma unroll
      for (int i = 0; i < 4; i++)
#pragma unroll
        for (int j = 0; j < 4; j++) {
          acc[i][j] = MFMA(afh[i], bfh[j], acc[i][j]);
          acc[i][j] = MFMA(afh[i], bfl[j], acc[i][j]);
          acc[i][j] = MFMA(afl[i], bfh[j], acc[i][j]);
        }
    } else {
#pragma unroll
      for (int i = 0; i < 4; i++)
#pragma unroll
        for (int j = 0; j < 4; j++)
          acc[i][j] = MFMA(afh[i], bfh[j], acc[i][j]);
    }
  }

  const int m0 = by*128 + wr*64;
  const int n0 = bx*128 + wc*64;
  if (MODE == 0) {
#pragma unroll
    for (int i = 0; i < 4; i++)
#pragma unroll
      for (int j = 0; j < 4; j++)
#pragma unroll
        for (int r = 0; r < 4; r++) {
          int m = m0 + i*16 + g*4 + r;
          int n = n0 + j*16 + i16;
          Cout[(size_t)m*N + n] = acc[i][j][r];
        }
  } else {
#pragma unroll
    for (int j = 0; j < 4; j++) {
      int n = n0 + j*16 + i16;
      int qkv = n / DMODEL;
      int rem = n - qkv*DMODEL;
      int h = rem >> 6, dh = rem & 63;
#pragma unroll
      for (int i = 0; i < 4; i++)
#pragma unroll
        for (int r = 0; r < 4; r++) {
          int m = m0 + i*16 + g*4 + r;
          int bb = m >> 10, ns = m & 1023;
          int bh = bb*NH + h;
          if (qkv < 2) {
            size_t dst = (((size_t)qkv*BHN + bh)*NSEQ + ns)*64 + dh;
            Cout[dst] = acc[i][j][r];
          } else {
            Vout[(((size_t)bh)*NSEQ + ns)*64 + dh] = f2bf(acc[i][j][r]);
          }
        }
    }
  }
}

// rows < 2*ROWS_PER: fp32 Q/K row -> rms-norm + scale + rope -> in-place interleaved [hi64|lo64] bf16
// rows >= 2*ROWS_PER: bf16 V row -> rms-norm -> transposed Vt [bh][64][1024] bf16
__global__ __launch_bounds__(256) void normrope_kernel(float* __restrict__ QKf,
                                                       const unsigned short* __restrict__ Vb,
                                                       unsigned short* __restrict__ Vt,
                                                       const int* __restrict__ pos_ids,
                                                       const float* __restrict__ q_scale,
                                                       const float* __restrict__ k_scale) {
  const int w = threadIdx.x >> 6, l = threadIdx.x & 63;
  const int row = blockIdx.x * 4 + w;                 // 0 .. 294911
  if (row < 2*ROWS_PER) {
    const int qkv = row / ROWS_PER;
    const int rem = row - qkv*ROWS_PER;
    const int bh = rem >> 10, ns = rem & 1023;
    const int b = bh / NH;
    float x = QKf[(size_t)row*64 + l];
    float ss = x * x;
#pragma unroll
    for (int d = 1; d < 64; d <<= 1) ss += __shfl_xor(ss, d);
    float xn = x * rsqrtf(ss * (1.0f/64.0f) + 1e-6f);
    xn *= (qkv == 0) ? q_scale[l] : k_scale[l];
    {
      int p = l >> 5, t = l & 31, idx = t & 15;
      float pos = (float)pos_ids[(b*NSEQ + ns)*2 + p];
      float ang = pos * __expf((float)idx * (-4.605170185988091f / 16.0f));
      float sn, cs;
      __sincosf(ang, &sn, &cs);
      float partner = __shfl_xor(xn, 16);
      xn = (t < 16) ? (xn*cs - partner*sn) : (xn*cs + partner*sn);
    }
    unsigned short hi = f2bf(xn);
    unsigned short lo = f2bf(xn - bf2f(hi));
    unsigned short* o = (unsigned short*)QKf + (size_t)row*128;
    o[l] = hi;
    o[64 + l] = lo;
  } else {
    const int vrow = row - 2*ROWS_PER;
    const int bh = vrow >> 10, ns = vrow & 1023;
    float x = bf2f(Vb[(size_t)vrow*64 + l]);
    float ss = x * x;
#pragma unroll
    for (int d = 1; d < 64; d <<= 1) ss += __shfl_xor(ss, d);
    float xn = x * rsqrtf(ss * (1.0f/64.0f) + 1e-6f);
    Vt[((size_t)bh*64 + l)*1024 + ns] = f2bf(xn);
  }
}

// flash attention: grid (16 qblocks, 96 bh), 4 waves x 16 q rows, KV tile = 64
// Q/K pre-split bf16 interleaved rows [hi64|lo64]; V pre-transposed bf16 [bh][64][1024]
__global__ __launch_bounds__(256) void attn_kernel(const unsigned short* __restrict__ QKu,
                                                   const unsigned short* __restrict__ Vtu,
                                                   unsigned short* __restrict__ O) {
  const int bh = blockIdx.y;
  const int q0 = blockIdx.x * 64;
  const int tid = threadIdx.x, w = tid >> 6, l = tid & 63;
  const int g = l >> 4, i16 = l & 15;
  const int b = bh / NH, h = bh - b*NH;
  const int sw = i16 & 7;

  __shared__ __align__(16) unsigned short Ks[64*128];   // [kv][hi64|lo64], chunk-swizzled
  __shared__ __align__(16) unsigned short Vs[64*64];    // [d][kv64], chunk-swizzled
  __shared__ __align__(16) unsigned short Pl[4][16*68];

  // Q fragments from interleaved split rows
  const unsigned short* qrow = QKu + ((size_t)bh*NSEQ + q0 + w*16 + i16)*128;
  bf16x8 qh0 = *(const bf16x8*)(qrow + g*8);
  bf16x8 qh1 = *(const bf16x8*)(qrow + 32 + g*8);
  bf16x8 ql0 = *(const bf16x8*)(qrow + 64 + g*8);
  bf16x8 ql1 = *(const bf16x8*)(qrow + 96 + g*8);

  // staging source pointers (XOR pre-swizzled global source, linear LDS dest)
  const unsigned short* Kbase = QKu + (size_t)(BHN + bh)*NSEQ*128;
  const unsigned short* Vtb   = Vtu + (size_t)bh*64*1024;
  const int cb = tid & 15;
  const int sck = ((cb & 7) ^ ((tid >> 4) & 7)) | (cb & 8);
  const unsigned short* pK = Kbase + (size_t)(tid >> 4)*128 + sck*8;
  const int cv = tid & 7;
  const int scv = cv ^ ((tid >> 3) & 7);
  const unsigned short* pV = Vtb + (size_t)(tid >> 3)*1024 + scv*8;
  unsigned short* ksw = Ks + w*512;   // wave-uniform LDS base
  unsigned short* vsw = Vs + w*512;

  const f32x4 fzero = {0.f, 0.f, 0.f, 0.f};
  float mR[4], lR[4];
  f32x4 o[4];
#pragma unroll
  for (int r = 0; r < 4; r++) { mR[r] = -1e30f; lR[r] = 0.f; }
#pragma unroll
  for (int t = 0; t < 4; t++) o[t] = fzero;

  for (int t = 0; t < 16; ++t) {
    __syncthreads();
    gload16(pK,        ksw);
    gload16(pK + 2048, ksw + 2048);
    gload16(pK + 4096, ksw + 4096);
    gload16(pK + 6144, ksw + 6144);
    gload16(pV,         vsw);
    gload16(pV + 32768, vsw + 2048);
    pK += 8192; pV += 64;
    __syncthreads();

    f32x4 s[4] = {fzero, fzero, fzero, fzero};
    __builtin_amdgcn_s_setprio(1);
#pragma unroll
    for (int j = 0; j < 4; ++j) {
      const unsigned short* kr = Ks + (j*16 + i16)*128;
      bf16x8 kh0 = *(const bf16x8*)(kr + (g ^ sw)*8);
      bf16x8 kh1 = *(const bf16x8*)(kr + ((4 + g) ^ sw)*8);
      bf16x8 kl0 = *(const bf16x8*)(kr + 64 + (g ^ sw)*8);
      bf16x8 kl1 = *(const bf16x8*)(kr + 64 + ((4 + g) ^ sw)*8);
      s[j] = MFMA(qh0, kh0, s[j]);
      s[j] = MFMA(qh1, kh1, s[j]);
      s[j] = MFMA(ql0, kh0, s[j]);
      s[j] = MFMA(ql1, kh1, s[j]);
      s[j] = MFMA(qh0, kl0, s[j]);
      s[j] = MFMA(qh1, kl1, s[j]);
    }
    __builtin_amdgcn_s_setprio(0);

    // online softmax with defer-max (THR=8)
    float nm[4];
    bool big = false;
#pragma unroll
    for (int r = 0; r < 4; ++r) {
      float tm = fmaxf(fmaxf(s[0][r], s[1][r]), fmaxf(s[2][r], s[3][r]));
#pragma unroll
      for (int d = 1; d < 16; d <<= 1) tm = fmaxf(tm, __shfl_xor(tm, d));
      nm[r] = fmaxf(mR[r], tm);
      big = big || (tm > mR[r] + 8.0f);
    }
    if (__any(big)) {
#pragma unroll
      for (int r = 0; r < 4; ++r) {
        float fac = __expf(mR[r] - nm[r]);
        mR[r] = nm[r];
        lR[r] *= fac;
#pragma unroll
        for (int t2 = 0; t2 < 4; ++t2) o[t2][r] *= fac;
      }
    }
#pragma unroll
    for (int r = 0; r < 4; ++r) {
      float rs = 0.f;
#pragma unroll
      for (int j = 0; j < 4; ++j) { s[j][r] = __expf(s[j][r] - mR[r]); rs += s[j][r]; }
#pragma unroll
      for (int d = 1; d < 16; d <<= 1) rs += __shfl_xor(rs, d);
      lR[r] += rs;
    }

    unsigned short* plw = &Pl[w][0];
#pragma unroll
    for (int j = 0; j < 4; ++j)
#pragma unroll
      for (int r = 0; r < 4; ++r)
        plw[(g*4 + r)*68 + j*16 + i16] = f2bf(s[j][r]);
    bf16x8 ap0 = *(const bf16x8*)(plw + i16*68 + g*8);
    bf16x8 ap1 = *(const bf16x8*)(plw + i16*68 + 32 + g*8);
    __builtin_amdgcn_s_setprio(1);
#pragma unroll
    for (int t2 = 0; t2 < 4; ++t2) {
      const unsigned short* vr = Vs + (t2*16 + i16)*64;
      bf16x8 bv0 = *(const bf16x8*)(vr + (g ^ sw)*8);
      bf16x8 bv1 = *(const bf16x8*)(vr + ((4 + g) ^ sw)*8);
      o[t2] = MFMA(ap0, bv0, o[t2]);
      o[t2] = MFMA(ap1, bv1, o[t2]);
    }
    __builtin_amdgcn_s_setprio(0);
  }

#pragma unroll
  for (int r = 0; r < 4; ++r) {
    float invl = 1.0f / lR[r];
    int q = q0 + w*16 + g*4 + r;
    size_t base = ((size_t)(b*NSEQ + q))*DMODEL + h*DHD;
#pragma unroll
    for (int t2 = 0; t2 < 4; ++t2)
      O[base + t2*16 + i16] = f2bf(o[t2][r] * invl);
  }
}

extern "C" void kernel_launch(void* const* d_in, const int* in_sizes, int n_in,
                              void* d_out, int out_size, void* d_ws, size_t ws_size,
                              hipStream_t stream) {
  const float* hs = (const float*)d_in[0];
  const int*   pos = (const int*)d_in[1];
  const float* Wq = (const float*)d_in[2];
  const float* Wk = (const float*)d_in[3];
  const float* Wv = (const float*)d_in[4];
  const float* Wo = (const float*)d_in[5];
  const float* qs = (const float*)d_in[6];
  const float* ks = (const float*)d_in[7];

  const int nhs = 8192*768;       // 6291456
  const int nw  = 768*768;        // 589824

  char* p = (char*)d_ws;
  unsigned short* Xh  = (unsigned short*)p; p += (size_t)nhs*2;   // -> Vt after gemm
  unsigned short* Xl  = (unsigned short*)p; p += (size_t)nhs*2;   // -> Ob after gemm
  unsigned short* Wh  = (unsigned short*)p; p += (size_t)3*nw*2;
  unsigned short* Wl  = (unsigned short*)p; p += (size_t)3*nw*2;
  unsigned short* Wob = (unsigned short*)p; p += (size_t)nw*2;
  float*          QKf = (float*)p;          p += (size_t)2*ROWS_PER*64*4; // Q,K fp32 -> split bf16 in place
  unsigned short* Vb  = (unsigned short*)p; p += (size_t)ROWS_PER*64*2;

  unsigned short* Vt = Xh;
  unsigned short* Ob = Xl;

  cast_split_kernel<<<nhs/1024, 256, 0, stream>>>(hs, Xh, Xl, nhs);
  cast_split_kernel<<<nw/1024, 256, 0, stream>>>(Wq, Wh, Wl, nw);
  cast_split_kernel<<<nw/1024, 256, 0, stream>>>(Wk, Wh + nw, Wl + nw, nw);
  cast_split_kernel<<<nw/1024, 256, 0, stream>>>(Wv, Wh + 2*nw, Wl + 2*nw, nw);
  cast_kernel<<<nw/1024, 256, 0, stream>>>(Wo, Wob, nw);

  gemm_bt<1><<<dim3(18, 64), 256, 0, stream>>>(Xh, Xl, Wh, Wl, QKf, Vb, 8192, 2304, 768);
  normrope_kernel<<<(3*ROWS_PER)/4, 256, 0, stream>>>(QKf, Vb, Vt, pos, qs, ks);
  attn_kernel<<<dim3(16, 96), 256, 0, stream>>>((const unsigned short*)QKf, Vt, Ob);
  gemm_bt<0><<<dim3(6, 64), 256, 0, stream>>>(Ob, nullptr, Wob, nullptr,
                                              (float*)d_out, nullptr, 8192, 768, 768);
}

// Round 4
// 261.190 us; speedup vs baseline: 1.3562x; 1.2797x over previous
//
#include <hip/hip_runtime.h>

typedef __attribute__((ext_vector_type(8))) short bf16x8;
typedef __attribute__((ext_vector_type(4))) float f32x4;

#define NH 12
#define DHD 64
#define NB 8
#define NSEQ 1024
#define DMODEL 768
#define BHN (NB*NH)            // 96
#define ROWS_PER (BHN*NSEQ)    // 98304

#define MFMA(a,b,c) __builtin_amdgcn_mfma_f32_16x16x32_bf16(a,b,c,0,0,0)

__device__ __forceinline__ unsigned short f2bf(float f) {
  unsigned int u = __float_as_uint(f);
  u += 0x7FFFu + ((u >> 16) & 1u);
  return (unsigned short)(u >> 16);
}
__device__ __forceinline__ float bf2f(unsigned short s) {
  return __uint_as_float(((unsigned int)s) << 16);
}

__device__ __forceinline__ void gload16(const void* g, void* l) {
  __builtin_amdgcn_global_load_lds(
      (__attribute__((address_space(1))) void*)(g),
      (__attribute__((address_space(3))) void*)(l), 16, 0, 0);
}

__global__ __launch_bounds__(256) void cast_kernel(const float* __restrict__ in,
                                                   unsigned short* __restrict__ out, int n) {
  int i = (blockIdx.x * blockDim.x + threadIdx.x) * 4;
  if (i < n) {
    float4 v = *(const float4*)(in + i);
    ushort4 o;
    o.x = f2bf(v.x); o.y = f2bf(v.y); o.z = f2bf(v.z); o.w = f2bf(v.w);
    *(ushort4*)(out + i) = o;
  }
}

__global__ __launch_bounds__(256) void cast_split_kernel(const float* __restrict__ in,
                                                         unsigned short* __restrict__ hi,
                                                         unsigned short* __restrict__ lo, int n) {
  int i = (blockIdx.x * blockDim.x + threadIdx.x) * 4;
  if (i < n) {
    float4 v = *(const float4*)(in + i);
    float vv[4] = {v.x, v.y, v.z, v.w};
    ushort4 h, l;
    unsigned short hs[4], ls[4];
#pragma unroll
    for (int e = 0; e < 4; e++) {
      hs[e] = f2bf(vv[e]);
      ls[e] = f2bf(vv[e] - bf2f(hs[e]));
    }
    h.x = hs[0]; h.y = hs[1]; h.z = hs[2]; h.w = hs[3];
    l.x = ls[0]; l.y = ls[1]; l.z = ls[2]; l.w = ls[3];
    *(ushort4*)(hi + i) = h;
    *(ushort4*)(lo + i) = l;
  }
}

// C = A(MxK) * B(NxK)^T
// MODE 0: plain bf16 (Ah,Bh) -> fp32 row-major C
// MODE 1: split hi/lo 3-term -> Q,K fp32 remapped [qkv][bh][ns][64]; V bf16 [bh][ns][64]
template<int MODE>
__global__ __launch_bounds__(256) void gemm_bt(const unsigned short* __restrict__ Ah,
                                               const unsigned short* __restrict__ Al,
                                               const unsigned short* __restrict__ Bh,
                                               const unsigned short* __restrict__ Bl,
                                               float* __restrict__ Cout,
                                               unsigned short* __restrict__ Vout,
                                               int M, int N, int K) {
  __shared__ __align__(16) unsigned short Ash[(MODE ? 2 : 1) * 128 * 32];
  __shared__ __align__(16) unsigned short Bsh[(MODE ? 2 : 1) * 128 * 32];
  const int tid = threadIdx.x;
  const int w = tid >> 6, l = tid & 63;
  const int wr = w >> 1, wc = w & 1;
  const int g = l >> 4, i16 = l & 15;
  const int bx = blockIdx.x, by = blockIdx.y;

  const f32x4 fzero = {0.f, 0.f, 0.f, 0.f};
  f32x4 acc[4][4];
#pragma unroll
  for (int i = 0; i < 4; i++)
#pragma unroll
    for (int j = 0; j < 4; j++) acc[i][j] = fzero;

  const size_t arow = (size_t)(by*128 + (tid >> 2))*K + (tid & 3)*8;
  const size_t brow = (size_t)(bx*128 + (tid >> 2))*K + (tid & 3)*8;
  char* AlB = (char*)Ash + w*1024;
  char* BlB = (char*)Bsh + w*1024;

  for (int k0 = 0; k0 < K; k0 += 32) {
    __syncthreads();
    gload16(Ah + arow + k0, AlB);
    gload16(Ah + arow + (size_t)64*K + k0, AlB + 4096);
    gload16(Bh + brow + k0, BlB);
    gload16(Bh + brow + (size_t)64*K + k0, BlB + 4096);
    if (MODE == 1) {
      gload16(Al + arow + k0, AlB + 8192);
      gload16(Al + arow + (size_t)64*K + k0, AlB + 8192 + 4096);
      gload16(Bl + brow + k0, BlB + 8192);
      gload16(Bl + brow + (size_t)64*K + k0, BlB + 8192 + 4096);
    }
    __syncthreads();
    bf16x8 afh[4], bfh[4];
#pragma unroll
    for (int i = 0; i < 4; i++)
      afh[i] = *(const bf16x8*)(Ash + (wr*64 + i*16 + i16)*32 + g*8);
#pragma unroll
    for (int j = 0; j < 4; j++)
      bfh[j] = *(const bf16x8*)(Bsh + (wc*64 + j*16 + i16)*32 + g*8);
    if (MODE == 1) {
      bf16x8 afl[4], bfl[4];
#pragma unroll
      for (int i = 0; i < 4; i++)
        afl[i] = *(const bf16x8*)(Ash + 4096 + (wr*64 + i*16 + i16)*32 + g*8);
#pragma unroll
      for (int j = 0; j < 4; j++)
        bfl[j] = *(const bf16x8*)(Bsh + 4096 + (wc*64 + j*16 + i16)*32 + g*8);
#pragma unroll
      for (int i = 0; i < 4; i++)
#pragma unroll
        for (int j = 0; j < 4; j++) {
          acc[i][j] = MFMA(afh[i], bfh[j], acc[i][j]);
          acc[i][j] = MFMA(afh[i], bfl[j], acc[i][j]);
          acc[i][j] = MFMA(afl[i], bfh[j], acc[i][j]);
        }
    } else {
#pragma unroll
      for (int i = 0; i < 4; i++)
#pragma unroll
        for (int j = 0; j < 4; j++)
          acc[i][j] = MFMA(afh[i], bfh[j], acc[i][j]);
    }
  }

  const int m0 = by*128 + wr*64;
  const int n0 = bx*128 + wc*64;
  if (MODE == 0) {
#pragma unroll
    for (int i = 0; i < 4; i++)
#pragma unroll
      for (int j = 0; j < 4; j++)
#pragma unroll
        for (int r = 0; r < 4; r++) {
          int m = m0 + i*16 + g*4 + r;
          int n = n0 + j*16 + i16;
          Cout[(size_t)m*N + n] = acc[i][j][r];
        }
  } else {
#pragma unroll
    for (int j = 0; j < 4; j++) {
      int n = n0 + j*16 + i16;
      int qkv = n / DMODEL;
      int rem = n - qkv*DMODEL;
      int h = rem >> 6, dh = rem & 63;
#pragma unroll
      for (int i = 0; i < 4; i++)
#pragma unroll
        for (int r = 0; r < 4; r++) {
          int m = m0 + i*16 + g*4 + r;
          int bb = m >> 10, ns = m & 1023;
          int bh = bb*NH + h;
          if (qkv < 2) {
            size_t dst = (((size_t)qkv*BHN + bh)*NSEQ + ns)*64 + dh;
            Cout[dst] = acc[i][j][r];
          } else {
            Vout[(((size_t)bh)*NSEQ + ns)*64 + dh] = f2bf(acc[i][j][r]);
          }
        }
    }
  }
}

// fp32 Q/K row -> rms-norm + scale + rope -> in-place interleaved [hi64|lo64] bf16
__global__ __launch_bounds__(256) void normrope_kernel(float* __restrict__ QKf,
                                                       const int* __restrict__ pos_ids,
                                                       const float* __restrict__ q_scale,
                                                       const float* __restrict__ k_scale) {
  const int w = threadIdx.x >> 6, l = threadIdx.x & 63;
  const int row = blockIdx.x * 4 + w;                 // 0 .. 2*ROWS_PER-1
  const int qkv = row / ROWS_PER;
  const int rem = row - qkv*ROWS_PER;
  const int bh = rem >> 10, ns = rem & 1023;
  const int b = bh / NH;
  float x = QKf[(size_t)row*64 + l];
  float ss = x * x;
#pragma unroll
  for (int d = 1; d < 64; d <<= 1) ss += __shfl_xor(ss, d);
  float xn = x * rsqrtf(ss * (1.0f/64.0f) + 1e-6f);
  xn *= (qkv == 0) ? q_scale[l] : k_scale[l];
  {
    int p = l >> 5, t = l & 31, idx = t & 15;
    float pos = (float)pos_ids[(b*NSEQ + ns)*2 + p];
    float ang = pos * __expf((float)idx * (-4.605170185988091f / 16.0f));
    float sn, cs;
    __sincosf(ang, &sn, &cs);
    float partner = __shfl_xor(xn, 16);
    xn = (t < 16) ? (xn*cs - partner*sn) : (xn*cs + partner*sn);
  }
  unsigned short hi = f2bf(xn);
  unsigned short lo = f2bf(xn - bf2f(hi));
  unsigned short* o = (unsigned short*)QKf + (size_t)row*128;
  o[l] = hi;
  o[64 + l] = lo;
}

// V: rms-norm + transpose [bh][ns][64] -> [bh][64][1024], LDS-tiled, coalesced
__global__ __launch_bounds__(256) void vtrans_kernel(const unsigned short* __restrict__ Vb,
                                                     unsigned short* __restrict__ Vt) {
  const int bh = blockIdx.y, ns0 = blockIdx.x * 64;
  const int tid = threadIdx.x;
  __shared__ __align__(16) unsigned short L[64*72];
  const int r = tid >> 2, part = tid & 3;
  const unsigned short* src = Vb + ((size_t)(bh*NSEQ + ns0 + r))*64 + part*16;
  float x[16];
  {
    uint4 a = *(const uint4*)(src);
    uint4 c = *(const uint4*)(src + 8);
    const unsigned short* ap = (const unsigned short*)&a;
    const unsigned short* cp2 = (const unsigned short*)&c;
#pragma unroll
    for (int e = 0; e < 8; ++e) { x[e] = bf2f(ap[e]); x[8+e] = bf2f(cp2[e]); }
  }
  float ss = 0.f;
#pragma unroll
  for (int e = 0; e < 16; ++e) ss += x[e]*x[e];
  ss += __shfl_xor(ss, 1);
  ss += __shfl_xor(ss, 2);
  float rinv = rsqrtf(ss * (1.0f/64.0f) + 1e-6f);
#pragma unroll
  for (int e = 0; e < 16; ++e)
    L[(part*16 + e)*72 + r] = f2bf(x[e] * rinv);
  __syncthreads();
  const int d = tid >> 2, ck = tid & 3;
  unsigned short* dst = Vt + ((size_t)bh*64 + d)*1024 + ns0 + ck*16;
  const unsigned short* lsrc = L + d*72 + ck*16;
  *(uint4*)(dst)     = *(const uint4*)(lsrc);
  *(uint4*)(dst + 8) = *(const uint4*)(lsrc + 8);
}

// sigma: LDS K-row p holds physical kv sigma(p); bit layout p={u,b,g,g,c,c} -> {u,g,g,b,c,c}
__device__ __forceinline__ int sigma_perm(int p) {
  return (p & 0x20) | ((p & 0xC) << 1) | ((p & 0x10) >> 2) | (p & 3);
}

// flash attention: grid (16 qblocks, 96 bh), 4 waves x 16 q rows, KV tile = 64
// swapped QK^T (K as A-operand) + sigma-permuted K staging => P stays in registers for PV.
// Q split hi/lo (2-term QK^T: Kh*Qh + Kh*Ql); V plain bf16 pre-transposed [bh][64][1024].
__global__ __launch_bounds__(256) void attn_kernel(const unsigned short* __restrict__ QKu,
                                                   const unsigned short* __restrict__ Vtu,
                                                   unsigned short* __restrict__ O) {
  const int bh = blockIdx.y;
  const int q0 = blockIdx.x * 64;
  const int tid = threadIdx.x, w = tid >> 6, l = tid & 63;
  const int g = l >> 4, i16 = l & 15;
  const int g4 = g*4;
  const int sw = i16 & 7;
  const int b = bh / NH, h = bh - b*NH;

  __shared__ __align__(16) unsigned short Ks[2*64*64];   // 2 x 8KB, swizzled chunks
  __shared__ __align__(16) unsigned short Vs[2*64*64];   // 2 x 8KB, swizzled chunks

  // Q fragments (own q-row = q0 + w*16 + i16), hi and lo
  const unsigned short* qrow = QKu + ((size_t)bh*NSEQ + q0 + w*16 + i16)*128;
  bf16x8 qh0 = *(const bf16x8*)(qrow + g*8);
  bf16x8 qh1 = *(const bf16x8*)(qrow + 32 + g*8);
  bf16x8 ql0 = *(const bf16x8*)(qrow + 64 + g*8);
  bf16x8 ql1 = *(const bf16x8*)(qrow + 96 + g*8);

  // staging pointers: K rows sigma-permuted, chunk-XOR-swizzled; V rows linear, chunk-swizzled
  const char* Kb  = (const char*)(QKu + (size_t)(BHN + bh)*NSEQ*128);
  const char* Vtb = (const char*)(Vtu + (size_t)bh*64*1024);
  const int prow0 = w*8 + (l >> 3);          // LDS row for issue 0 (issue 1: +32)
  const int cl = (l & 7) ^ (l >> 3);         // swizzled logical chunk
  const char* Ksrc0 = Kb + sigma_perm(prow0)*256 + cl*16;
  const char* Ksrc1 = Kb + (sigma_perm(prow0) + 32)*256 + cl*16;
  const char* Vsrc0 = Vtb + prow0*2048 + cl*16;
  const char* Vsrc1 = Vtb + (prow0 + 32)*2048 + cl*16;

  const f32x4 fzero = {0.f, 0.f, 0.f, 0.f};
  float mR = -1e30f, lR = 0.f;
  f32x4 o[4];
#pragma unroll
  for (int t = 0; t < 4; t++) o[t] = fzero;

  int cur = 0;
  {
    char* kd = (char*)Ks + w*1024;
    char* vd = (char*)Vs + w*1024;
    gload16(Ksrc0, kd);
    gload16(Ksrc1, kd + 4096);
    gload16(Vsrc0, vd);
    gload16(Vsrc1, vd + 4096);
  }
  __syncthreads();

  for (int t = 0; t < 16; ++t) {
    if (t < 15) {
      char* kd = (char*)Ks + (cur^1)*8192 + w*1024;
      char* vd = (char*)Vs + (cur^1)*8192 + w*1024;
      gload16(Ksrc0 + (t+1)*16384, kd);
      gload16(Ksrc1 + (t+1)*16384, kd + 4096);
      gload16(Vsrc0 + (t+1)*128,   vd);
      gload16(Vsrc1 + (t+1)*128,   vd + 4096);
    }
    const unsigned short* Kc = Ks + cur*4096;
    const unsigned short* Vc = Vs + cur*4096;

    f32x4 s[4] = {fzero, fzero, fzero, fzero};
    __builtin_amdgcn_s_setprio(1);
#pragma unroll
    for (int j = 0; j < 4; ++j) {
      const unsigned short* kr = Kc + (j*16 + i16)*64;
      bf16x8 kh0 = *(const bf16x8*)(kr + (g ^ sw)*8);
      bf16x8 kh1 = *(const bf16x8*)(kr + ((g^4) ^ sw)*8);
      s[j] = MFMA(kh0, qh0, s[j]);
      s[j] = MFMA(kh1, qh1, s[j]);
      s[j] = MFMA(kh0, ql0, s[j]);
      s[j] = MFMA(kh1, ql1, s[j]);
    }
    __builtin_amdgcn_s_setprio(0);

    // per-lane row stats over 16 values + cross-g reduce
    float tm = fmaxf(
        fmaxf(fmaxf(fmaxf(s[0][0],s[0][1]), fmaxf(s[0][2],s[0][3])),
              fmaxf(fmaxf(s[1][0],s[1][1]), fmaxf(s[1][2],s[1][3]))),
        fmaxf(fmaxf(fmaxf(s[2][0],s[2][1]), fmaxf(s[2][2],s[2][3])),
              fmaxf(fmaxf(s[3][0],s[3][1]), fmaxf(s[3][2],s[3][3]))));
    tm = fmaxf(tm, __shfl_xor(tm, 16));
    tm = fmaxf(tm, __shfl_xor(tm, 32));
    if (__any(tm > mR + 8.0f)) {          // defer-max
      float nm = fmaxf(mR, tm);
      float fac = __expf(mR - nm);
      mR = nm;
      lR *= fac;
#pragma unroll
      for (int r = 0; r < 4; ++r) {
        float fr = __shfl(fac, g4 + r);
        o[0][r] *= fr; o[1][r] *= fr; o[2][r] *= fr; o[3][r] *= fr;
      }
    }
    float rs = 0.f;
#pragma unroll
    for (int j = 0; j < 4; ++j)
#pragma unroll
      for (int r = 0; r < 4; ++r) { s[j][r] = __expf(s[j][r] - mR); rs += s[j][r]; }
    rs += __shfl_xor(rs, 16);
    rs += __shfl_xor(rs, 32);
    lR += rs;

    // pack P -> PV A-fragments (sigma matching makes this a plain concat)
    bf16x8 pa0, pa1;
#pragma unroll
    for (int e = 0; e < 4; ++e) {
      pa0[e]   = (short)f2bf(s[0][e]);
      pa0[4+e] = (short)f2bf(s[1][e]);
      pa1[e]   = (short)f2bf(s[2][e]);
      pa1[4+e] = (short)f2bf(s[3][e]);
    }
    __builtin_amdgcn_s_setprio(1);
#pragma unroll
    for (int t2 = 0; t2 < 4; ++t2) {
      const unsigned short* vr = Vc + (t2*16 + i16)*64;
      bf16x8 bv0 = *(const bf16x8*)(vr + (g ^ sw)*8);
      bf16x8 bv1 = *(const bf16x8*)(vr + ((g^4) ^ sw)*8);
      o[t2] = MFMA(pa0, bv0, o[t2]);
      o[t2] = MFMA(pa1, bv1, o[t2]);
    }
    __builtin_amdgcn_s_setprio(0);

    __syncthreads();
    cur ^= 1;
  }

#pragma unroll
  for (int r = 0; r < 4; ++r) {
    float lr = __shfl(lR, g4 + r);
    float invl = 1.0f / lr;
    int q = q0 + w*16 + g4 + r;
    size_t base = ((size_t)(b*NSEQ + q))*DMODEL + h*DHD;
#pragma unroll
    for (int t2 = 0; t2 < 4; ++t2)
      O[base + t2*16 + i16] = f2bf(o[t2][r] * invl);
  }
}

extern "C" void kernel_launch(void* const* d_in, const int* in_sizes, int n_in,
                              void* d_out, int out_size, void* d_ws, size_t ws_size,
                              hipStream_t stream) {
  const float* hs = (const float*)d_in[0];
  const int*   pos = (const int*)d_in[1];
  const float* Wq = (const float*)d_in[2];
  const float* Wk = (const float*)d_in[3];
  const float* Wv = (const float*)d_in[4];
  const float* Wo = (const float*)d_in[5];
  const float* qs = (const float*)d_in[6];
  const float* ks = (const float*)d_in[7];

  const int nhs = 8192*768;       // 6291456
  const int nw  = 768*768;        // 589824

  char* p = (char*)d_ws;
  unsigned short* Xh  = (unsigned short*)p; p += (size_t)nhs*2;   // -> Vt after gemm
  unsigned short* Xl  = (unsigned short*)p; p += (size_t)nhs*2;   // -> Ob after gemm
  unsigned short* Wh  = (unsigned short*)p; p += (size_t)3*nw*2;
  unsigned short* Wl  = (unsigned short*)p; p += (size_t)3*nw*2;
  unsigned short* Wob = (unsigned short*)p; p += (size_t)nw*2;
  float*          QKf = (float*)p;          p += (size_t)2*ROWS_PER*64*4;
  unsigned short* Vb  = (unsigned short*)p; p += (size_t)ROWS_PER*64*2;

  unsigned short* Vt = Xh;
  unsigned short* Ob = Xl;

  cast_split_kernel<<<nhs/1024, 256, 0, stream>>>(hs, Xh, Xl, nhs);
  cast_split_kernel<<<nw/1024, 256, 0, stream>>>(Wq, Wh, Wl, nw);
  cast_split_kernel<<<nw/1024, 256, 0, stream>>>(Wk, Wh + nw, Wl + nw, nw);
  cast_split_kernel<<<nw/1024, 256, 0, stream>>>(Wv, Wh + 2*nw, Wl + 2*nw, nw);
  cast_kernel<<<nw/1024, 256, 0, stream>>>(Wo, Wob, nw);

  gemm_bt<1><<<dim3(18, 64), 256, 0, stream>>>(Xh, Xl, Wh, Wl, QKf, Vb, 8192, 2304, 768);
  normrope_kernel<<<(2*ROWS_PER)/4, 256, 0, stream>>>(QKf, pos, qs, ks);
  vtrans_kernel<<<dim3(16, 96), 256, 0, stream>>>(Vb, Vt);
  attn_kernel<<<dim3(16, 96), 256, 0, stream>>>((const unsigned short*)QKf, Vt, Ob);
  gemm_bt<0><<<dim3(6, 64), 256, 0, stream>>>(Ob, nullptr, Wob, nullptr,
                                              (float*)d_out, nullptr, 8192, 768, 768);
}

// Round 5
// 215.931 us; speedup vs baseline: 1.6404x; 1.2096x over previous
//
#include <hip/hip_runtime.h>

typedef __attribute__((ext_vector_type(8))) short bf16x8;
typedef __attribute__((ext_vector_type(4))) float f32x4;

#define NH 12
#define DHD 64
#define NB 8
#define NSEQ 1024
#define DMODEL 768
#define BHN (NB*NH)            // 96
#define ROWS_PER (BHN*NSEQ)    // 98304

#define MFMA(a,b,c) __builtin_amdgcn_mfma_f32_16x16x32_bf16(a,b,c,0,0,0)

__device__ __forceinline__ unsigned short f2bf(float f) {
  unsigned int u = __float_as_uint(f);
  u += 0x7FFFu + ((u >> 16) & 1u);
  return (unsigned short)(u >> 16);
}
__device__ __forceinline__ float bf2f(unsigned short s) {
  return __uint_as_float(((unsigned int)s) << 16);
}

__device__ __forceinline__ void gload16(const void* g, void* l) {
  __builtin_amdgcn_global_load_lds(
      (__attribute__((address_space(1))) void*)(g),
      (__attribute__((address_space(3))) void*)(l), 16, 0, 0);
}

__global__ __launch_bounds__(256) void cast_kernel(const float* __restrict__ in,
                                                   unsigned short* __restrict__ out, int n) {
  int i = (blockIdx.x * blockDim.x + threadIdx.x) * 4;
  if (i < n) {
    float4 v = *(const float4*)(in + i);
    ushort4 o;
    o.x = f2bf(v.x); o.y = f2bf(v.y); o.z = f2bf(v.z); o.w = f2bf(v.w);
    *(ushort4*)(out + i) = o;
  }
}

__global__ __launch_bounds__(256) void cast_split_kernel(const float* __restrict__ in,
                                                         unsigned short* __restrict__ hi,
                                                         unsigned short* __restrict__ lo, int n) {
  int i = (blockIdx.x * blockDim.x + threadIdx.x) * 4;
  if (i < n) {
    float4 v = *(const float4*)(in + i);
    float vv[4] = {v.x, v.y, v.z, v.w};
    ushort4 h, l;
    unsigned short hs[4], ls[4];
#pragma unroll
    for (int e = 0; e < 4; e++) {
      hs[e] = f2bf(vv[e]);
      ls[e] = f2bf(vv[e] - bf2f(hs[e]));
    }
    h.x = hs[0]; h.y = hs[1]; h.z = hs[2]; h.w = hs[3];
    l.x = ls[0]; l.y = ls[1]; l.z = ls[2]; l.w = ls[3];
    *(ushort4*)(hi + i) = h;
    *(ushort4*)(lo + i) = l;
  }
}

// C = A(MxK) * B(NxK)^T
// MODE 0: plain bf16 (Ah,Bh) -> fp32 row-major C (grid 384 = 6x64)
// MODE 1: QKV (grid 1152 = 18x64). bx<12 (Q,K): 3-term split GEMM + fused
//         rms-norm+scale+rope+hi/lo-split epilogue -> packed ushort rows
//         [qkv][bh][ns][hi64|lo64]. bx>=12 (V): 1-term, bf16 [bh][ns][64].
template<int MODE>
__global__ __launch_bounds__(256) void gemm_bt(const unsigned short* __restrict__ Ah,
                                               const unsigned short* __restrict__ Al,
                                               const unsigned short* __restrict__ Bh,
                                               const unsigned short* __restrict__ Bl,
                                               float* __restrict__ Cout,
                                               unsigned short* __restrict__ QKout,
                                               unsigned short* __restrict__ Vout,
                                               const int* __restrict__ pos_ids,
                                               const float* __restrict__ q_scale,
                                               const float* __restrict__ k_scale,
                                               int M, int N, int K) {
  __shared__ __align__(16) unsigned short Ash[(MODE ? 2 : 1) * 128 * 32];
  __shared__ __align__(16) unsigned short Bsh[(MODE ? 2 : 1) * 128 * 32];
  const int tid = threadIdx.x;
  const int w = tid >> 6, l = tid & 63;
  const int wr = w >> 1, wc = w & 1;
  const int g = l >> 4, i16 = l & 15;

  // XCD-aware bijective swizzle (grid%8==0 in both modes)
  int bx, by;
  {
    int id = blockIdx.x;
    const int nbx = (MODE == 1) ? 18 : 6;
    const int chunk = (MODE == 1) ? 144 : 48;
    int idp = (id & 7) * chunk + (id >> 3);
    by = idp / nbx; bx = idp - by * nbx;
  }
  const bool isV = (MODE == 1) && (bx >= 12);

  const f32x4 fzero = {0.f, 0.f, 0.f, 0.f};
  f32x4 acc[4][4];
#pragma unroll
  for (int i = 0; i < 4; i++)
#pragma unroll
    for (int j = 0; j < 4; j++) acc[i][j] = fzero;

  const size_t arow = (size_t)(by*128 + (tid >> 2))*K + (tid & 3)*8;
  const size_t brow = (size_t)(bx*128 + (tid >> 2))*K + (tid & 3)*8;
  char* AlB = (char*)Ash + w*1024;
  char* BlB = (char*)Bsh + w*1024;

  for (int k0 = 0; k0 < K; k0 += 32) {
    __syncthreads();
    gload16(Ah + arow + k0, AlB);
    gload16(Ah + arow + (size_t)64*K + k0, AlB + 4096);
    gload16(Bh + brow + k0, BlB);
    gload16(Bh + brow + (size_t)64*K + k0, BlB + 4096);
    if (MODE == 1 && !isV) {
      gload16(Al + arow + k0, AlB + 8192);
      gload16(Al + arow + (size_t)64*K + k0, AlB + 8192 + 4096);
      gload16(Bl + brow + k0, BlB + 8192);
      gload16(Bl + brow + (size_t)64*K + k0, BlB + 8192 + 4096);
    }
    __syncthreads();
    bf16x8 afh[4], bfh[4];
#pragma unroll
    for (int i = 0; i < 4; i++)
      afh[i] = *(const bf16x8*)(Ash + (wr*64 + i*16 + i16)*32 + g*8);
#pragma unroll
    for (int j = 0; j < 4; j++)
      bfh[j] = *(const bf16x8*)(Bsh + (wc*64 + j*16 + i16)*32 + g*8);
    if (MODE == 1 && !isV) {
      bf16x8 afl[4], bfl[4];
#pragma unroll
      for (int i = 0; i < 4; i++)
        afl[i] = *(const bf16x8*)(Ash + 4096 + (wr*64 + i*16 + i16)*32 + g*8);
#pragma unroll
      for (int j = 0; j < 4; j++)
        bfl[j] = *(const bf16x8*)(Bsh + 4096 + (wc*64 + j*16 + i16)*32 + g*8);
#pragma unroll
      for (int i = 0; i < 4; i++)
#pragma unroll
        for (int j = 0; j < 4; j++) {
          acc[i][j] = MFMA(afh[i], bfh[j], acc[i][j]);
          acc[i][j] = MFMA(afh[i], bfl[j], acc[i][j]);
          acc[i][j] = MFMA(afl[i], bfh[j], acc[i][j]);
        }
    } else {
#pragma unroll
      for (int i = 0; i < 4; i++)
#pragma unroll
        for (int j = 0; j < 4; j++)
          acc[i][j] = MFMA(afh[i], bfh[j], acc[i][j]);
    }
  }

  const int m0 = by*128 + wr*64;
  const int n0 = bx*128 + wc*64;
  if (MODE == 0) {
#pragma unroll
    for (int i = 0; i < 4; i++)
#pragma unroll
      for (int j = 0; j < 4; j++)
#pragma unroll
        for (int r = 0; r < 4; r++) {
          int m = m0 + i*16 + g*4 + r;
          int n = n0 + j*16 + i16;
          Cout[(size_t)m*N + n] = acc[i][j][r];
        }
  } else if (isV) {
    const int h = (n0 - 2*DMODEL) >> 6;
#pragma unroll
    for (int j = 0; j < 4; j++) {
      int dh = j*16 + i16;
#pragma unroll
      for (int i = 0; i < 4; i++)
#pragma unroll
        for (int r = 0; r < 4; r++) {
          int m = m0 + i*16 + g*4 + r;
          int bb = m >> 10, ns = m & 1023;
          Vout[(((size_t)(bb*NH + h))*NSEQ + ns)*64 + dh] = f2bf(acc[i][j][r]);
        }
    }
  } else {
    // fused rms-norm + scale + 2D rope + hi/lo split for Q (qkv=0) / K (qkv=1)
    const int qkv = n0 / DMODEL;
    const int h = (n0 - qkv*DMODEL) >> 6;
    const float* scp = (qkv == 0) ? q_scale : k_scale;
    float scl[4];
#pragma unroll
    for (int j = 0; j < 4; j++) scl[j] = scp[j*16 + i16];
    const float invf = __expf((float)i16 * (-4.605170185988091f / 16.0f));
#pragma unroll
    for (int i = 0; i < 4; i++) {
      f32x4 ssv = fzero;
#pragma unroll
      for (int j = 0; j < 4; j++)
#pragma unroll
        for (int r = 0; r < 4; r++) ssv[r] += acc[i][j][r]*acc[i][j][r];
#pragma unroll
      for (int d = 1; d < 16; d <<= 1)
#pragma unroll
        for (int r = 0; r < 4; r++) ssv[r] += __shfl_xor(ssv[r], d);
#pragma unroll
      for (int r = 0; r < 4; r++) {
        int m = m0 + i*16 + g*4 + r;
        int bb = m >> 10, ns = m & 1023;
        float rinv = rsqrtf(ssv[r] * (1.0f/64.0f) + 1e-6f);
        int2 pp = *(const int2*)(pos_ids + ((size_t)bb*NSEQ + ns)*2);
        float sn0, cs0, sn1, cs1;
        __sincosf((float)pp.x * invf, &sn0, &cs0);
        __sincosf((float)pp.y * invf, &sn1, &cs1);
        float x0 = acc[i][0][r]*rinv*scl[0];
        float x1 = acc[i][1][r]*rinv*scl[1];
        float x2 = acc[i][2][r]*rinv*scl[2];
        float x3 = acc[i][3][r]*rinv*scl[3];
        float o0 = x0*cs0 - x1*sn0;
        float o1 = x1*cs0 + x0*sn0;
        float o2 = x2*cs1 - x3*sn1;
        float o3 = x3*cs1 + x2*sn1;
        size_t row = ((size_t)qkv*BHN + bb*NH + h)*NSEQ + ns;
        unsigned short* ob = QKout + row*128;
        unsigned short h0 = f2bf(o0), h1 = f2bf(o1), h2 = f2bf(o2), h3 = f2bf(o3);
        ob[i16]      = h0; ob[16 + i16] = h1;
        ob[32 + i16] = h2; ob[48 + i16] = h3;
        ob[64 + i16] = f2bf(o0 - bf2f(h0));
        ob[80 + i16] = f2bf(o1 - bf2f(h1));
        ob[96 + i16] = f2bf(o2 - bf2f(h2));
        ob[112 + i16] = f2bf(o3 - bf2f(h3));
      }
    }
  }
}

// V: rms-norm + transpose [bh][ns][64] -> [bh][64][1024], LDS-tiled, coalesced
__global__ __launch_bounds__(256) void vtrans_kernel(const unsigned short* __restrict__ Vb,
                                                     unsigned short* __restrict__ Vt) {
  const int bh = blockIdx.y, ns0 = blockIdx.x * 64;
  const int tid = threadIdx.x;
  __shared__ __align__(16) unsigned short L[64*72];
  const int r = tid >> 2, part = tid & 3;
  const unsigned short* src = Vb + ((size_t)(bh*NSEQ + ns0 + r))*64 + part*16;
  float x[16];
  {
    uint4 a = *(const uint4*)(src);
    uint4 c = *(const uint4*)(src + 8);
    const unsigned short* ap = (const unsigned short*)&a;
    const unsigned short* cp2 = (const unsigned short*)&c;
#pragma unroll
    for (int e = 0; e < 8; ++e) { x[e] = bf2f(ap[e]); x[8+e] = bf2f(cp2[e]); }
  }
  float ss = 0.f;
#pragma unroll
  for (int e = 0; e < 16; ++e) ss += x[e]*x[e];
  ss += __shfl_xor(ss, 1);
  ss += __shfl_xor(ss, 2);
  float rinv = rsqrtf(ss * (1.0f/64.0f) + 1e-6f);
#pragma unroll
  for (int e = 0; e < 16; ++e)
    L[(part*16 + e)*72 + r] = f2bf(x[e] * rinv);
  __syncthreads();
  const int d = tid >> 2, ck = tid & 3;
  unsigned short* dst = Vt + ((size_t)bh*64 + d)*1024 + ns0 + ck*16;
  const unsigned short* lsrc = L + d*72 + ck*16;
  *(uint4*)(dst)     = *(const uint4*)(lsrc);
  *(uint4*)(dst + 8) = *(const uint4*)(lsrc + 8);
}

// sigma: LDS K-row p holds physical kv sigma(p); bit layout p={u,b,g,g,c,c} -> {u,g,g,b,c,c}
__device__ __forceinline__ int sigma_perm(int p) {
  return (p & 0x20) | ((p & 0xC) << 1) | ((p & 0x10) >> 2) | (p & 3);
}

// flash attention: grid (16 qblocks, 96 bh), 4 waves x 16 q rows, KV tile = 64
__global__ __launch_bounds__(256) void attn_kernel(const unsigned short* __restrict__ QKu,
                                                   const unsigned short* __restrict__ Vtu,
                                                   unsigned short* __restrict__ O) {
  const int bh = blockIdx.y;
  const int q0 = blockIdx.x * 64;
  const int tid = threadIdx.x, w = tid >> 6, l = tid & 63;
  const int g = l >> 4, i16 = l & 15;
  const int g4 = g*4;
  const int sw = i16 & 7;
  const int b = bh / NH, h = bh - b*NH;

  __shared__ __align__(16) unsigned short Ks[2*64*64];
  __shared__ __align__(16) unsigned short Vs[2*64*64];

  const unsigned short* qrow = QKu + ((size_t)bh*NSEQ + q0 + w*16 + i16)*128;
  bf16x8 qh0 = *(const bf16x8*)(qrow + g*8);
  bf16x8 qh1 = *(const bf16x8*)(qrow + 32 + g*8);
  bf16x8 ql0 = *(const bf16x8*)(qrow + 64 + g*8);
  bf16x8 ql1 = *(const bf16x8*)(qrow + 96 + g*8);

  const char* Kb  = (const char*)(QKu + (size_t)(BHN + bh)*NSEQ*128);
  const char* Vtb = (const char*)(Vtu + (size_t)bh*64*1024);
  const int prow0 = w*8 + (l >> 3);
  const int cl = (l & 7) ^ (l >> 3);
  const char* Ksrc0 = Kb + sigma_perm(prow0)*256 + cl*16;
  const char* Ksrc1 = Kb + (sigma_perm(prow0) + 32)*256 + cl*16;
  const char* Vsrc0 = Vtb + prow0*2048 + cl*16;
  const char* Vsrc1 = Vtb + (prow0 + 32)*2048 + cl*16;

  const f32x4 fzero = {0.f, 0.f, 0.f, 0.f};
  float mR = -1e30f, lR = 0.f;
  f32x4 o[4];
#pragma unroll
  for (int t = 0; t < 4; t++) o[t] = fzero;

  int cur = 0;
  {
    char* kd = (char*)Ks + w*1024;
    char* vd = (char*)Vs + w*1024;
    gload16(Ksrc0, kd);
    gload16(Ksrc1, kd + 4096);
    gload16(Vsrc0, vd);
    gload16(Vsrc1, vd + 4096);
  }
  __syncthreads();

  for (int t = 0; t < 16; ++t) {
    if (t < 15) {
      char* kd = (char*)Ks + (cur^1)*8192 + w*1024;
      char* vd = (char*)Vs + (cur^1)*8192 + w*1024;
      gload16(Ksrc0 + (t+1)*16384, kd);
      gload16(Ksrc1 + (t+1)*16384, kd + 4096);
      gload16(Vsrc0 + (t+1)*128,   vd);
      gload16(Vsrc1 + (t+1)*128,   vd + 4096);
    }
    const unsigned short* Kc = Ks + cur*4096;
    const unsigned short* Vc = Vs + cur*4096;

    f32x4 s[4] = {fzero, fzero, fzero, fzero};
    __builtin_amdgcn_s_setprio(1);
#pragma unroll
    for (int j = 0; j < 4; ++j) {
      const unsigned short* kr = Kc + (j*16 + i16)*64;
      bf16x8 kh0 = *(const bf16x8*)(kr + (g ^ sw)*8);
      bf16x8 kh1 = *(const bf16x8*)(kr + ((g^4) ^ sw)*8);
      s[j] = MFMA(kh0, qh0, s[j]);
      s[j] = MFMA(kh1, qh1, s[j]);
      s[j] = MFMA(kh0, ql0, s[j]);
      s[j] = MFMA(kh1, ql1, s[j]);
    }
    __builtin_amdgcn_s_setprio(0);

    float tm = fmaxf(
        fmaxf(fmaxf(fmaxf(s[0][0],s[0][1]), fmaxf(s[0][2],s[0][3])),
              fmaxf(fmaxf(s[1][0],s[1][1]), fmaxf(s[1][2],s[1][3]))),
        fmaxf(fmaxf(fmaxf(s[2][0],s[2][1]), fmaxf(s[2][2],s[2][3])),
              fmaxf(fmaxf(s[3][0],s[3][1]), fmaxf(s[3][2],s[3][3]))));
    tm = fmaxf(tm, __shfl_xor(tm, 16));
    tm = fmaxf(tm, __shfl_xor(tm, 32));
    if (__any(tm > mR + 8.0f)) {
      float nm = fmaxf(mR, tm);
      float fac = __expf(mR - nm);
      mR = nm;
      lR *= fac;
#pragma unroll
      for (int r = 0; r < 4; ++r) {
        float fr = __shfl(fac, g4 + r);
        o[0][r] *= fr; o[1][r] *= fr; o[2][r] *= fr; o[3][r] *= fr;
      }
    }
    float rs = 0.f;
#pragma unroll
    for (int j = 0; j < 4; ++j)
#pragma unroll
      for (int r = 0; r < 4; ++r) { s[j][r] = __expf(s[j][r] - mR); rs += s[j][r]; }
    rs += __shfl_xor(rs, 16);
    rs += __shfl_xor(rs, 32);
    lR += rs;

    bf16x8 pa0, pa1;
#pragma unroll
    for (int e = 0; e < 4; ++e) {
      pa0[e]   = (short)f2bf(s[0][e]);
      pa0[4+e] = (short)f2bf(s[1][e]);
      pa1[e]   = (short)f2bf(s[2][e]);
      pa1[4+e] = (short)f2bf(s[3][e]);
    }
    __builtin_amdgcn_s_setprio(1);
#pragma unroll
    for (int t2 = 0; t2 < 4; ++t2) {
      const unsigned short* vr = Vc + (t2*16 + i16)*64;
      bf16x8 bv0 = *(const bf16x8*)(vr + (g ^ sw)*8);
      bf16x8 bv1 = *(const bf16x8*)(vr + ((g^4) ^ sw)*8);
      o[t2] = MFMA(pa0, bv0, o[t2]);
      o[t2] = MFMA(pa1, bv1, o[t2]);
    }
    __builtin_amdgcn_s_setprio(0);

    __syncthreads();
    cur ^= 1;
  }

#pragma unroll
  for (int r = 0; r < 4; ++r) {
    float lr = __shfl(lR, g4 + r);
    float invl = 1.0f / lr;
    int q = q0 + w*16 + g4 + r;
    size_t base = ((size_t)(b*NSEQ + q))*DMODEL + h*DHD;
#pragma unroll
    for (int t2 = 0; t2 < 4; ++t2)
      O[base + t2*16 + i16] = f2bf(o[t2][r] * invl);
  }
}

extern "C" void kernel_launch(void* const* d_in, const int* in_sizes, int n_in,
                              void* d_out, int out_size, void* d_ws, size_t ws_size,
                              hipStream_t stream) {
  const float* hs = (const float*)d_in[0];
  const int*   pos = (const int*)d_in[1];
  const float* Wq = (const float*)d_in[2];
  const float* Wk = (const float*)d_in[3];
  const float* Wv = (const float*)d_in[4];
  const float* Wo = (const float*)d_in[5];
  const float* qs = (const float*)d_in[6];
  const float* ks = (const float*)d_in[7];

  const int nhs = 8192*768;       // 6291456
  const int nw  = 768*768;        // 589824

  char* p = (char*)d_ws;
  unsigned short* Xh  = (unsigned short*)p; p += (size_t)nhs*2;   // -> Vt after gemm
  unsigned short* Xl  = (unsigned short*)p; p += (size_t)nhs*2;   // -> Ob after gemm
  unsigned short* Wh  = (unsigned short*)p; p += (size_t)3*nw*2;
  unsigned short* Wl  = (unsigned short*)p; p += (size_t)2*nw*2;
  unsigned short* Wob = (unsigned short*)p; p += (size_t)nw*2;
  unsigned short* QKpk= (unsigned short*)p; p += (size_t)2*ROWS_PER*128*2;
  unsigned short* Vb  = (unsigned short*)p; p += (size_t)ROWS_PER*64*2;

  unsigned short* Vt = Xh;
  unsigned short* Ob = Xl;

  cast_split_kernel<<<nhs/1024, 256, 0, stream>>>(hs, Xh, Xl, nhs);
  cast_split_kernel<<<nw/1024, 256, 0, stream>>>(Wq, Wh, Wl, nw);
  cast_split_kernel<<<nw/1024, 256, 0, stream>>>(Wk, Wh + nw, Wl + nw, nw);
  cast_kernel<<<nw/1024, 256, 0, stream>>>(Wv, Wh + 2*nw, nw);
  cast_kernel<<<nw/1024, 256, 0, stream>>>(Wo, Wob, nw);

  gemm_bt<1><<<1152, 256, 0, stream>>>(Xh, Xl, Wh, Wl, nullptr, QKpk, Vb,
                                       pos, qs, ks, 8192, 2304, 768);
  vtrans_kernel<<<dim3(16, 96), 256, 0, stream>>>(Vb, Vt);
  attn_kernel<<<dim3(16, 96), 256, 0, stream>>>(QKpk, Vt, Ob);
  gemm_bt<0><<<384, 256, 0, stream>>>(Ob, nullptr, Wob, nullptr,
                                      (float*)d_out, nullptr, nullptr,
                                      nullptr, nullptr, nullptr, 8192, 768, 768);
}

// Round 6
// 164.750 us; speedup vs baseline: 2.1501x; 1.3107x over previous
//
#include <hip/hip_runtime.h>

typedef _Float16 f16;
typedef __attribute__((ext_vector_type(8))) _Float16 f16x8;
typedef __attribute__((ext_vector_type(4))) _Float16 f16x4;
typedef __attribute__((ext_vector_type(4))) float f32x4;

#define NH 12
#define DHD 64
#define NB 8
#define NSEQ 1024
#define DMODEL 768
#define BHN (NB*NH)            // 96
#define ROWS_PER (BHN*NSEQ)    // 98304

#define MFMA(a,b,c) __builtin_amdgcn_mfma_f32_16x16x32_f16(a,b,c,0,0,0)

__device__ __forceinline__ void gload16(const void* g, void* l) {
  __builtin_amdgcn_global_load_lds(
      (__attribute__((address_space(1))) void*)(g),
      (__attribute__((address_space(3))) void*)(l), 16, 0, 0);
}

__global__ __launch_bounds__(256) void cast_kernel(const float* __restrict__ in,
                                                   f16* __restrict__ out, int n) {
  int i = (blockIdx.x * blockDim.x + threadIdx.x) * 4;
  if (i < n) {
    float4 v = *(const float4*)(in + i);
    f16x4 o = {(f16)v.x, (f16)v.y, (f16)v.z, (f16)v.w};
    *(f16x4*)(out + i) = o;
  }
}

// C = A(MxK) * B(NxK)^T, all fp16 inputs.
// MODE 0: fp32 row-major C (grid 384 = 6x64)
// MODE 1: QKV (grid 1152 = 18x64). bx<12 (Q,K): fused rms-norm+scale+rope
//         epilogue -> fp16 rows [qk][bh][ns][64]. bx>=12 (V): fp16 [bh][ns][64].
template<int MODE>
__global__ __launch_bounds__(256) void gemm_bt(const f16* __restrict__ A,
                                               const f16* __restrict__ B,
                                               float* __restrict__ Cout,
                                               f16* __restrict__ QKout,
                                               f16* __restrict__ Vout,
                                               const int* __restrict__ pos_ids,
                                               const float* __restrict__ q_scale,
                                               const float* __restrict__ k_scale,
                                               int M, int N, int K) {
  __shared__ __align__(16) f16 Ash[128*32];
  __shared__ __align__(16) f16 Bsh[128*32];
  const int tid = threadIdx.x;
  const int w = tid >> 6, l = tid & 63;
  const int wr = w >> 1, wc = w & 1;
  const int g = l >> 4, i16 = l & 15;

  // XCD-aware bijective swizzle (grid%8==0 in both modes)
  int bx, by;
  {
    int id = blockIdx.x;
    const int nbx = (MODE == 1) ? 18 : 6;
    const int chunk = (MODE == 1) ? 144 : 48;
    int idp = (id & 7) * chunk + (id >> 3);
    by = idp / nbx; bx = idp - by * nbx;
  }

  const f32x4 fzero = {0.f, 0.f, 0.f, 0.f};
  f32x4 acc[4][4];
#pragma unroll
  for (int i = 0; i < 4; i++)
#pragma unroll
    for (int j = 0; j < 4; j++) acc[i][j] = fzero;

  const size_t arow = (size_t)(by*128 + (tid >> 2))*K + (tid & 3)*8;
  const size_t brow = (size_t)(bx*128 + (tid >> 2))*K + (tid & 3)*8;
  char* AlB = (char*)Ash + w*1024;
  char* BlB = (char*)Bsh + w*1024;

  for (int k0 = 0; k0 < K; k0 += 32) {
    __syncthreads();
    gload16(A + arow + k0, AlB);
    gload16(A + arow + (size_t)64*K + k0, AlB + 4096);
    gload16(B + brow + k0, BlB);
    gload16(B + brow + (size_t)64*K + k0, BlB + 4096);
    __syncthreads();
    f16x8 af[4], bfr[4];
#pragma unroll
    for (int i = 0; i < 4; i++)
      af[i] = *(const f16x8*)(Ash + (wr*64 + i*16 + i16)*32 + g*8);
#pragma unroll
    for (int j = 0; j < 4; j++)
      bfr[j] = *(const f16x8*)(Bsh + (wc*64 + j*16 + i16)*32 + g*8);
#pragma unroll
    for (int i = 0; i < 4; i++)
#pragma unroll
      for (int j = 0; j < 4; j++)
        acc[i][j] = MFMA(af[i], bfr[j], acc[i][j]);
  }

  const int m0 = by*128 + wr*64;
  const int n0 = bx*128 + wc*64;
  if (MODE == 0) {
#pragma unroll
    for (int i = 0; i < 4; i++)
#pragma unroll
      for (int j = 0; j < 4; j++)
#pragma unroll
        for (int r = 0; r < 4; r++) {
          int m = m0 + i*16 + g*4 + r;
          int n = n0 + j*16 + i16;
          Cout[(size_t)m*N + n] = acc[i][j][r];
        }
  } else if (n0 >= 2*DMODEL) {
    const int h = (n0 - 2*DMODEL) >> 6;
#pragma unroll
    for (int j = 0; j < 4; j++) {
      int dh = j*16 + i16;
#pragma unroll
      for (int i = 0; i < 4; i++)
#pragma unroll
        for (int r = 0; r < 4; r++) {
          int m = m0 + i*16 + g*4 + r;
          int bb = m >> 10, ns = m & 1023;
          Vout[(((size_t)(bb*NH + h))*NSEQ + ns)*64 + dh] = (f16)acc[i][j][r];
        }
    }
  } else {
    // fused rms-norm + scale + 2D rope for Q (qkv=0) / K (qkv=1), fp16 out
    const int qkv = n0 / DMODEL;
    const int h = (n0 - qkv*DMODEL) >> 6;
    const float* scp = (qkv == 0) ? q_scale : k_scale;
    float scl[4];
#pragma unroll
    for (int j = 0; j < 4; j++) scl[j] = scp[j*16 + i16];
    const float invf = __expf((float)i16 * (-4.605170185988091f / 16.0f));
#pragma unroll
    for (int i = 0; i < 4; i++) {
      f32x4 ssv = fzero;
#pragma unroll
      for (int j = 0; j < 4; j++)
#pragma unroll
        for (int r = 0; r < 4; r++) ssv[r] += acc[i][j][r]*acc[i][j][r];
#pragma unroll
      for (int d = 1; d < 16; d <<= 1)
#pragma unroll
        for (int r = 0; r < 4; r++) ssv[r] += __shfl_xor(ssv[r], d);
#pragma unroll
      for (int r = 0; r < 4; r++) {
        int m = m0 + i*16 + g*4 + r;
        int bb = m >> 10, ns = m & 1023;
        float rinv = rsqrtf(ssv[r] * (1.0f/64.0f) + 1e-6f);
        int2 pp = *(const int2*)(pos_ids + ((size_t)bb*NSEQ + ns)*2);
        float sn0, cs0, sn1, cs1;
        __sincosf((float)pp.x * invf, &sn0, &cs0);
        __sincosf((float)pp.y * invf, &sn1, &cs1);
        float x0 = acc[i][0][r]*rinv*scl[0];
        float x1 = acc[i][1][r]*rinv*scl[1];
        float x2 = acc[i][2][r]*rinv*scl[2];
        float x3 = acc[i][3][r]*rinv*scl[3];
        size_t row = ((size_t)qkv*BHN + bb*NH + h)*NSEQ + ns;
        f16* ob = QKout + row*64;
        ob[i16]      = (f16)(x0*cs0 - x1*sn0);
        ob[16 + i16] = (f16)(x1*cs0 + x0*sn0);
        ob[32 + i16] = (f16)(x2*cs1 - x3*sn1);
        ob[48 + i16] = (f16)(x3*cs1 + x2*sn1);
      }
    }
  }
}

// V: rms-norm + transpose [bh][ns][64] -> [bh][64][1024], LDS-tiled, coalesced
__global__ __launch_bounds__(256) void vtrans_kernel(const f16* __restrict__ Vb,
                                                     f16* __restrict__ Vt) {
  const int bh = blockIdx.y, ns0 = blockIdx.x * 64;
  const int tid = threadIdx.x;
  __shared__ __align__(16) f16 L[64*72];
  const int r = tid >> 2, part = tid & 3;
  const f16* src = Vb + ((size_t)(bh*NSEQ + ns0 + r))*64 + part*16;
  float x[16];
  {
    f16x8 a = *(const f16x8*)(src);
    f16x8 c = *(const f16x8*)(src + 8);
#pragma unroll
    for (int e = 0; e < 8; ++e) { x[e] = (float)a[e]; x[8+e] = (float)c[e]; }
  }
  float ss = 0.f;
#pragma unroll
  for (int e = 0; e < 16; ++e) ss += x[e]*x[e];
  ss += __shfl_xor(ss, 1);
  ss += __shfl_xor(ss, 2);
  float rinv = rsqrtf(ss * (1.0f/64.0f) + 1e-6f);
#pragma unroll
  for (int e = 0; e < 16; ++e)
    L[(part*16 + e)*72 + r] = (f16)(x[e] * rinv);
  __syncthreads();
  const int d = tid >> 2, ck = tid & 3;
  f16* dst = Vt + ((size_t)bh*64 + d)*1024 + ns0 + ck*16;
  const f16* lsrc = L + d*72 + ck*16;
  *(uint4*)(dst)     = *(const uint4*)(lsrc);
  *(uint4*)(dst + 8) = *(const uint4*)(lsrc + 8);
}

// sigma: LDS K-row p holds physical kv sigma(p); bit layout p={u,b,g,g,c,c} -> {u,g,g,b,c,c}
__device__ __forceinline__ int sigma_perm(int p) {
  return (p & 0x20) | ((p & 0xC) << 1) | ((p & 0x10) >> 2) | (p & 3);
}

// flash attention: grid (16 qblocks, 96 bh), 4 waves x 16 q rows, KV tile = 64
// swapped QK^T (K as A-operand) + sigma-permuted K staging => P stays in registers.
__global__ __launch_bounds__(256) void attn_kernel(const f16* __restrict__ QKu,
                                                   const f16* __restrict__ Vtu,
                                                   f16* __restrict__ O) {
  const int bh = blockIdx.y;
  const int q0 = blockIdx.x * 64;
  const int tid = threadIdx.x, w = tid >> 6, l = tid & 63;
  const int g = l >> 4, i16 = l & 15;
  const int g4 = g*4;
  const int sw = i16 & 7;
  const int b = bh / NH, h = bh - b*NH;

  __shared__ __align__(16) f16 Ks[2*64*64];
  __shared__ __align__(16) f16 Vs[2*64*64];

  const f16* qrow = QKu + ((size_t)bh*NSEQ + q0 + w*16 + i16)*64;
  f16x8 q0f = *(const f16x8*)(qrow + g*8);
  f16x8 q1f = *(const f16x8*)(qrow + 32 + g*8);

  const char* Kb  = (const char*)(QKu + (size_t)(BHN + bh)*NSEQ*64);
  const char* Vtb = (const char*)(Vtu + (size_t)bh*64*1024);
  const int prow0 = w*8 + (l >> 3);
  const int cl = (l & 7) ^ (l >> 3);
  const char* Ksrc0 = Kb + sigma_perm(prow0)*128 + cl*16;
  const char* Ksrc1 = Kb + (sigma_perm(prow0) + 32)*128 + cl*16;
  const char* Vsrc0 = Vtb + prow0*2048 + cl*16;
  const char* Vsrc1 = Vtb + (prow0 + 32)*2048 + cl*16;

  const f32x4 fzero = {0.f, 0.f, 0.f, 0.f};
  float mR = -1e30f, lR = 0.f;
  f32x4 o[4];
#pragma unroll
  for (int t = 0; t < 4; t++) o[t] = fzero;

  int cur = 0;
  {
    char* kd = (char*)Ks + w*1024;
    char* vd = (char*)Vs + w*1024;
    gload16(Ksrc0, kd);
    gload16(Ksrc1, kd + 4096);
    gload16(Vsrc0, vd);
    gload16(Vsrc1, vd + 4096);
  }
  __syncthreads();

  for (int t = 0; t < 16; ++t) {
    if (t < 15) {
      char* kd = (char*)Ks + (cur^1)*8192 + w*1024;
      char* vd = (char*)Vs + (cur^1)*8192 + w*1024;
      gload16(Ksrc0 + (t+1)*8192, kd);
      gload16(Ksrc1 + (t+1)*8192, kd + 4096);
      gload16(Vsrc0 + (t+1)*128,  vd);
      gload16(Vsrc1 + (t+1)*128,  vd + 4096);
    }
    const f16* Kc = Ks + cur*4096;
    const f16* Vc = Vs + cur*4096;

    f32x4 s[4] = {fzero, fzero, fzero, fzero};
    __builtin_amdgcn_s_setprio(1);
#pragma unroll
    for (int j = 0; j < 4; ++j) {
      const f16* kr = Kc + (j*16 + i16)*64;
      f16x8 k0 = *(const f16x8*)(kr + (g ^ sw)*8);
      f16x8 k1 = *(const f16x8*)(kr + ((g^4) ^ sw)*8);
      s[j] = MFMA(k0, q0f, s[j]);
      s[j] = MFMA(k1, q1f, s[j]);
    }
    __builtin_amdgcn_s_setprio(0);

    float tm = fmaxf(
        fmaxf(fmaxf(fmaxf(s[0][0],s[0][1]), fmaxf(s[0][2],s[0][3])),
              fmaxf(fmaxf(s[1][0],s[1][1]), fmaxf(s[1][2],s[1][3]))),
        fmaxf(fmaxf(fmaxf(s[2][0],s[2][1]), fmaxf(s[2][2],s[2][3])),
              fmaxf(fmaxf(s[3][0],s[3][1]), fmaxf(s[3][2],s[3][3]))));
    tm = fmaxf(tm, __shfl_xor(tm, 16));
    tm = fmaxf(tm, __shfl_xor(tm, 32));
    if (__any(tm > mR + 8.0f)) {
      float nm = fmaxf(mR, tm);
      float fac = __expf(mR - nm);
      mR = nm;
      lR *= fac;
#pragma unroll
      for (int r = 0; r < 4; ++r) {
        float fr = __shfl(fac, g4 + r);
        o[0][r] *= fr; o[1][r] *= fr; o[2][r] *= fr; o[3][r] *= fr;
      }
    }
    float rs = 0.f;
#pragma unroll
    for (int j = 0; j < 4; ++j)
#pragma unroll
      for (int r = 0; r < 4; ++r) { s[j][r] = __expf(s[j][r] - mR); rs += s[j][r]; }
    rs += __shfl_xor(rs, 16);
    rs += __shfl_xor(rs, 32);
    lR += rs;

    f16x8 pa0, pa1;
#pragma unroll
    for (int e = 0; e < 4; ++e) {
      pa0[e]   = (f16)s[0][e];
      pa0[4+e] = (f16)s[1][e];
      pa1[e]   = (f16)s[2][e];
      pa1[4+e] = (f16)s[3][e];
    }
    __builtin_amdgcn_s_setprio(1);
#pragma unroll
    for (int t2 = 0; t2 < 4; ++t2) {
      const f16* vr = Vc + (t2*16 + i16)*64;
      f16x8 bv0 = *(const f16x8*)(vr + (g ^ sw)*8);
      f16x8 bv1 = *(const f16x8*)(vr + ((g^4) ^ sw)*8);
      o[t2] = MFMA(pa0, bv0, o[t2]);
      o[t2] = MFMA(pa1, bv1, o[t2]);
    }
    __builtin_amdgcn_s_setprio(0);

    __syncthreads();
    cur ^= 1;
  }

#pragma unroll
  for (int r = 0; r < 4; ++r) {
    float lr = __shfl(lR, g4 + r);
    float invl = 1.0f / lr;
    int q = q0 + w*16 + g4 + r;
    size_t base = ((size_t)(b*NSEQ + q))*DMODEL + h*DHD;
#pragma unroll
    for (int t2 = 0; t2 < 4; ++t2)
      O[base + t2*16 + i16] = (f16)(o[t2][r] * invl);
  }
}

extern "C" void kernel_launch(void* const* d_in, const int* in_sizes, int n_in,
                              void* d_out, int out_size, void* d_ws, size_t ws_size,
                              hipStream_t stream) {
  const float* hs = (const float*)d_in[0];
  const int*   pos = (const int*)d_in[1];
  const float* Wq = (const float*)d_in[2];
  const float* Wk = (const float*)d_in[3];
  const float* Wv = (const float*)d_in[4];
  const float* Wo = (const float*)d_in[5];
  const float* qs = (const float*)d_in[6];
  const float* ks = (const float*)d_in[7];

  const int nhs = 8192*768;       // 6291456
  const int nw  = 768*768;        // 589824

  char* p = (char*)d_ws;
  f16* Xf   = (f16*)p; p += (size_t)nhs*2;          // -> Vt after gemm
  f16* Wf   = (f16*)p; p += (size_t)3*nw*2;         // Wq|Wk|Wv
  f16* Wof  = (f16*)p; p += (size_t)nw*2;
  f16* QKpk = (f16*)p; p += (size_t)2*ROWS_PER*64*2;
  f16* Vb   = (f16*)p; p += (size_t)ROWS_PER*64*2;
  f16* Ob   = (f16*)p; p += (size_t)nhs*2;

  f16* Vt = Xf;   // alias: Xf dead after QKV GEMM

  cast_kernel<<<nhs/1024, 256, 0, stream>>>(hs, Xf, nhs);
  cast_kernel<<<nw/1024, 256, 0, stream>>>(Wq, Wf, nw);
  cast_kernel<<<nw/1024, 256, 0, stream>>>(Wk, Wf + nw, nw);
  cast_kernel<<<nw/1024, 256, 0, stream>>>(Wv, Wf + 2*nw, nw);
  cast_kernel<<<nw/1024, 256, 0, stream>>>(Wo, Wof, nw);

  gemm_bt<1><<<1152, 256, 0, stream>>>(Xf, Wf, nullptr, QKpk, Vb,
                                       pos, qs, ks, 8192, 2304, 768);
  vtrans_kernel<<<dim3(16, 96), 256, 0, stream>>>(Vb, Vt);
  attn_kernel<<<dim3(16, 96), 256, 0, stream>>>(QKpk, Vt, Ob);
  gemm_bt<0><<<384, 256, 0, stream>>>(Ob, Wof, (float*)d_out, nullptr, nullptr,
                                      nullptr, nullptr, nullptr, 8192, 768, 768);
}

// Round 7
// 143.655 us; speedup vs baseline: 2.4658x; 1.1468x over previous
//
#include <hip/hip_runtime.h>

typedef _Float16 f16;
typedef __attribute__((ext_vector_type(8))) _Float16 f16x8;
typedef __attribute__((ext_vector_type(4))) _Float16 f16x4;
typedef __attribute__((ext_vector_type(4))) float f32x4;

#define NH 12
#define DHD 64
#define NB 8
#define NSEQ 1024
#define DMODEL 768
#define BHN (NB*NH)            // 96
#define ROWS_PER (BHN*NSEQ)    // 98304

#define MFMA(a,b,c) __builtin_amdgcn_mfma_f32_16x16x32_f16(a,b,c,0,0,0)

__device__ __forceinline__ void gload16(const void* g, void* l) {
  __builtin_amdgcn_global_load_lds(
      (__attribute__((address_space(1))) void*)(g),
      (__attribute__((address_space(3))) void*)(l), 16, 0, 0);
}

__global__ __launch_bounds__(256) void cast_kernel(const float* __restrict__ in,
                                                   f16* __restrict__ out, int n) {
  int i = (blockIdx.x * blockDim.x + threadIdx.x) * 4;
  if (i < n) {
    float4 v = *(const float4*)(in + i);
    f16x4 o = {(f16)v.x, (f16)v.y, (f16)v.z, (f16)v.w};
    *(f16x4*)(out + i) = o;
  }
}

// fused cast of all four weight matrices (each nw elements)
__global__ __launch_bounds__(256) void cast_w_kernel(const float* __restrict__ Wq,
                                                     const float* __restrict__ Wk,
                                                     const float* __restrict__ Wv,
                                                     const float* __restrict__ Wo,
                                                     f16* __restrict__ Wf,
                                                     f16* __restrict__ Wof, int nw) {
  int i = (blockIdx.x * blockDim.x + threadIdx.x) * 4;
  if (i < 4*nw) {
    int which = i / nw;
    int off = i - which*nw;
    const float* src = (which == 0) ? Wq : (which == 1) ? Wk : (which == 2) ? Wv : Wo;
    f16* dst = (which < 3) ? (Wf + (size_t)which*nw + off) : (Wof + off);
    float4 v = *(const float4*)(src + off);
    f16x4 o = {(f16)v.x, (f16)v.y, (f16)v.z, (f16)v.w};
    *(f16x4*)dst = o;
  }
}

// C = A(MxK) * B(NxK)^T, fp16 inputs, BK=64, XOR-swizzled LDS.
// MODE 0: fp32 row-major C (grid 384 = 6x64)
// MODE 1: QKV (grid 1152 = 18x64). bx<12 (Q,K): fused rms-norm+scale+rope
//         epilogue -> fp16 rows [qk][bh][ns][64]. bx>=12 (V): fused rms-norm
//         + LDS transpose -> Vout [bh][64][1024] fp16.
template<int MODE>
__global__ __launch_bounds__(256) void gemm_bt(const f16* __restrict__ A,
                                               const f16* __restrict__ B,
                                               float* __restrict__ Cout,
                                               f16* __restrict__ QKout,
                                               f16* __restrict__ Vout,
                                               const int* __restrict__ pos_ids,
                                               const float* __restrict__ q_scale,
                                               const float* __restrict__ k_scale,
                                               int M, int N, int K) {
  // staging: A[128][64] + B[128][64] = 16384 f16; V-transpose: [128][136] = 17408 f16
  __shared__ __align__(16) f16 SH[(MODE == 1) ? 17408 : 16384];
  f16* Ash = SH;
  f16* Bsh = SH + 8192;
  const int tid = threadIdx.x;
  const int w = tid >> 6, l = tid & 63;
  const int wr = w >> 1, wc = w & 1;
  const int g = l >> 4, i16 = l & 15;

  // XCD-aware bijective swizzle (grid%8==0 in both modes)
  int bx, by;
  {
    int id = blockIdx.x;
    const int nbx = (MODE == 1) ? 18 : 6;
    const int chunk = (MODE == 1) ? 144 : 48;
    int idp = (id & 7) * chunk + (id >> 3);
    by = idp / nbx; bx = idp - by * nbx;
  }
  const bool isV = (MODE == 1) && (bx >= 12);

  const f32x4 fzero = {0.f, 0.f, 0.f, 0.f};
  f32x4 acc[4][4];
#pragma unroll
  for (int i = 0; i < 4; i++)
#pragma unroll
    for (int j = 0; j < 4; j++) acc[i][j] = fzero;

  // staging: issue n covers rows n*32+(tid>>3); source chunk pre-swizzled by row&7
  const int srow = tid >> 3;
  const int schunk = (tid & 7) ^ (srow & 7);
  const size_t arow = (size_t)(by*128 + srow)*K + schunk*8;
  const size_t brow = (size_t)(bx*128 + srow)*K + schunk*8;
  char* AlB = (char*)Ash + w*1024;
  char* BlB = (char*)Bsh + w*1024;

  for (int k0 = 0; k0 < K; k0 += 64) {
    __syncthreads();
#pragma unroll
    for (int n = 0; n < 4; ++n) {
      gload16(A + arow + (size_t)(n*32)*K + k0, AlB + n*4096);
      gload16(B + brow + (size_t)(n*32)*K + k0, BlB + n*4096);
    }
    __syncthreads();
#pragma unroll
    for (int kk = 0; kk < 2; ++kk) {
      f16x8 af[4], bfr[4];
#pragma unroll
      for (int i = 0; i < 4; i++)
        af[i] = *(const f16x8*)(Ash + (wr*64 + i*16 + i16)*64 + ((kk*4 + g) ^ (i16 & 7))*8);
#pragma unroll
      for (int j = 0; j < 4; j++)
        bfr[j] = *(const f16x8*)(Bsh + (wc*64 + j*16 + i16)*64 + ((kk*4 + g) ^ (i16 & 7))*8);
#pragma unroll
      for (int i = 0; i < 4; i++)
#pragma unroll
        for (int j = 0; j < 4; j++)
          acc[i][j] = MFMA(af[i], bfr[j], acc[i][j]);
    }
  }

  const int m0 = by*128 + wr*64;
  const int n0 = bx*128 + wc*64;
  if (MODE == 0) {
#pragma unroll
    for (int i = 0; i < 4; i++)
#pragma unroll
      for (int j = 0; j < 4; j++)
#pragma unroll
        for (int r = 0; r < 4; r++) {
          int m = m0 + i*16 + g*4 + r;
          int n = n0 + j*16 + i16;
          Cout[(size_t)m*N + n] = acc[i][j][r];
        }
  } else if (isV) {
    // V: rms-norm + LDS transpose -> Vout [bh][64][1024]
    const int h0 = (bx - 12)*2;
    const int bb = by >> 3;
    const int ns0 = (by & 7) * 128;
    f16* Lt = SH;                       // [128 dh][136]
    __syncthreads();                    // all waves done with staging LDS
#pragma unroll
    for (int i = 0; i < 4; i++) {
      f32x4 ssv = fzero;
#pragma unroll
      for (int j = 0; j < 4; j++)
#pragma unroll
        for (int r = 0; r < 4; r++) ssv[r] += acc[i][j][r]*acc[i][j][r];
#pragma unroll
      for (int d = 1; d < 16; d <<= 1)
#pragma unroll
        for (int r = 0; r < 4; r++) ssv[r] += __shfl_xor(ssv[r], d);
#pragma unroll
      for (int r = 0; r < 4; r++) {
        float rinv = rsqrtf(ssv[r] * (1.0f/64.0f) + 1e-6f);
        int nsl = wr*64 + i*16 + g*4 + r;
#pragma unroll
        for (int j = 0; j < 4; j++)
          Lt[(wc*64 + j*16 + i16)*136 + nsl] = (f16)(acc[i][j][r]*rinv);
      }
    }
    __syncthreads();
    const int dh = tid >> 1, half = tid & 1;
    f16* dst = Vout + ((size_t)((bb*NH + h0 + (dh >> 6))*64 + (dh & 63)))*1024
               + ns0 + half*64;
    const f16* ls = Lt + dh*136 + half*64;
#pragma unroll
    for (int e = 0; e < 8; ++e)
      *(uint4*)(dst + e*8) = *(const uint4*)(ls + e*8);
  } else {
    // fused rms-norm + scale + 2D rope for Q (qkv=0) / K (qkv=1), fp16 out
    const int qkv = n0 / DMODEL;
    const int h = (n0 - qkv*DMODEL) >> 6;
    const float* scp = (qkv == 0) ? q_scale : k_scale;
    float scl[4];
#pragma unroll
    for (int j = 0; j < 4; j++) scl[j] = scp[j*16 + i16];
    const float invf = __expf((float)i16 * (-4.605170185988091f / 16.0f));
#pragma unroll
    for (int i = 0; i < 4; i++) {
      f32x4 ssv = fzero;
#pragma unroll
      for (int j = 0; j < 4; j++)
#pragma unroll
        for (int r = 0; r < 4; r++) ssv[r] += acc[i][j][r]*acc[i][j][r];
#pragma unroll
      for (int d = 1; d < 16; d <<= 1)
#pragma unroll
        for (int r = 0; r < 4; r++) ssv[r] += __shfl_xor(ssv[r], d);
#pragma unroll
      for (int r = 0; r < 4; r++) {
        int m = m0 + i*16 + g*4 + r;
        int bb = m >> 10, ns = m & 1023;
        float rinv = rsqrtf(ssv[r] * (1.0f/64.0f) + 1e-6f);
        int2 pp = *(const int2*)(pos_ids + ((size_t)bb*NSEQ + ns)*2);
        float sn0, cs0, sn1, cs1;
        __sincosf((float)pp.x * invf, &sn0, &cs0);
        __sincosf((float)pp.y * invf, &sn1, &cs1);
        float x0 = acc[i][0][r]*rinv*scl[0];
        float x1 = acc[i][1][r]*rinv*scl[1];
        float x2 = acc[i][2][r]*rinv*scl[2];
        float x3 = acc[i][3][r]*rinv*scl[3];
        size_t row = ((size_t)qkv*BHN + bb*NH + h)*NSEQ + ns;
        f16* ob = QKout + row*64;
        ob[i16]      = (f16)(x0*cs0 - x1*sn0);
        ob[16 + i16] = (f16)(x1*cs0 + x0*sn0);
        ob[32 + i16] = (f16)(x2*cs1 - x3*sn1);
        ob[48 + i16] = (f16)(x3*cs1 + x2*sn1);
      }
    }
  }
}

// sigma: LDS K-row p holds physical kv sigma(p); bit layout p={u,b,g,g,c,c} -> {u,g,g,b,c,c}
__device__ __forceinline__ int sigma_perm(int p) {
  return (p & 0x20) | ((p & 0xC) << 1) | ((p & 0x10) >> 2) | (p & 3);
}

// flash attention: grid (16 qblocks, 96 bh), 4 waves x 16 q rows, KV tile = 64
// swapped QK^T (K as A-operand) + sigma-permuted K staging => P stays in registers.
__global__ __launch_bounds__(256) void attn_kernel(const f16* __restrict__ QKu,
                                                   const f16* __restrict__ Vtu,
                                                   f16* __restrict__ O) {
  const int bh = blockIdx.y;
  const int q0 = blockIdx.x * 64;
  const int tid = threadIdx.x, w = tid >> 6, l = tid & 63;
  const int g = l >> 4, i16 = l & 15;
  const int g4 = g*4;
  const int sw = i16 & 7;
  const int b = bh / NH, h = bh - b*NH;

  __shared__ __align__(16) f16 Ks[2*64*64];
  __shared__ __align__(16) f16 Vs[2*64*64];

  const f16* qrow = QKu + ((size_t)bh*NSEQ + q0 + w*16 + i16)*64;
  f16x8 q0f = *(const f16x8*)(qrow + g*8);
  f16x8 q1f = *(const f16x8*)(qrow + 32 + g*8);

  const char* Kb  = (const char*)(QKu + (size_t)(BHN + bh)*NSEQ*64);
  const char* Vtb = (const char*)(Vtu + (size_t)bh*64*1024);
  const int prow0 = w*8 + (l >> 3);
  const int cl = (l & 7) ^ (l >> 3);
  const char* Ksrc0 = Kb + sigma_perm(prow0)*128 + cl*16;
  const char* Ksrc1 = Kb + (sigma_perm(prow0) + 32)*128 + cl*16;
  const char* Vsrc0 = Vtb + prow0*2048 + cl*16;
  const char* Vsrc1 = Vtb + (prow0 + 32)*2048 + cl*16;

  const f32x4 fzero = {0.f, 0.f, 0.f, 0.f};
  float mR = -1e30f, lR = 0.f;
  f32x4 o[4];
#pragma unroll
  for (int t = 0; t < 4; t++) o[t] = fzero;

  int cur = 0;
  {
    char* kd = (char*)Ks + w*1024;
    char* vd = (char*)Vs + w*1024;
    gload16(Ksrc0, kd);
    gload16(Ksrc1, kd + 4096);
    gload16(Vsrc0, vd);
    gload16(Vsrc1, vd + 4096);
  }
  __syncthreads();

  for (int t = 0; t < 16; ++t) {
    if (t < 15) {
      char* kd = (char*)Ks + (cur^1)*8192 + w*1024;
      char* vd = (char*)Vs + (cur^1)*8192 + w*1024;
      gload16(Ksrc0 + (t+1)*8192, kd);
      gload16(Ksrc1 + (t+1)*8192, kd + 4096);
      gload16(Vsrc0 + (t+1)*128,  vd);
      gload16(Vsrc1 + (t+1)*128,  vd + 4096);
    }
    const f16* Kc = Ks + cur*4096;
    const f16* Vc = Vs + cur*4096;

    f32x4 s[4] = {fzero, fzero, fzero, fzero};
    __builtin_amdgcn_s_setprio(1);
#pragma unroll
    for (int j = 0; j < 4; ++j) {
      const f16* kr = Kc + (j*16 + i16)*64;
      f16x8 k0 = *(const f16x8*)(kr + (g ^ sw)*8);
      f16x8 k1 = *(const f16x8*)(kr + ((g^4) ^ sw)*8);
      s[j] = MFMA(k0, q0f, s[j]);
      s[j] = MFMA(k1, q1f, s[j]);
    }
    __builtin_amdgcn_s_setprio(0);

    float tm = fmaxf(
        fmaxf(fmaxf(fmaxf(s[0][0],s[0][1]), fmaxf(s[0][2],s[0][3])),
              fmaxf(fmaxf(s[1][0],s[1][1]), fmaxf(s[1][2],s[1][3]))),
        fmaxf(fmaxf(fmaxf(s[2][0],s[2][1]), fmaxf(s[2][2],s[2][3])),
              fmaxf(fmaxf(s[3][0],s[3][1]), fmaxf(s[3][2],s[3][3]))));
    tm = fmaxf(tm, __shfl_xor(tm, 16));
    tm = fmaxf(tm, __shfl_xor(tm, 32));
    if (__any(tm > mR + 8.0f)) {
      float nm = fmaxf(mR, tm);
      float fac = __expf(mR - nm);
      mR = nm;
      lR *= fac;
#pragma unroll
      for (int r = 0; r < 4; ++r) {
        float fr = __shfl(fac, g4 + r);
        o[0][r] *= fr; o[1][r] *= fr; o[2][r] *= fr; o[3][r] *= fr;
      }
    }
    float rs = 0.f;
#pragma unroll
    for (int j = 0; j < 4; ++j)
#pragma unroll
      for (int r = 0; r < 4; ++r) { s[j][r] = __expf(s[j][r] - mR); rs += s[j][r]; }
    rs += __shfl_xor(rs, 16);
    rs += __shfl_xor(rs, 32);
    lR += rs;

    f16x8 pa0, pa1;
#pragma unroll
    for (int e = 0; e < 4; ++e) {
      pa0[e]   = (f16)s[0][e];
      pa0[4+e] = (f16)s[1][e];
      pa1[e]   = (f16)s[2][e];
      pa1[4+e] = (f16)s[3][e];
    }
    __builtin_amdgcn_s_setprio(1);
#pragma unroll
    for (int t2 = 0; t2 < 4; ++t2) {
      const f16* vr = Vc + (t2*16 + i16)*64;
      f16x8 bv0 = *(const f16x8*)(vr + (g ^ sw)*8);
      f16x8 bv1 = *(const f16x8*)(vr + ((g^4) ^ sw)*8);
      o[t2] = MFMA(pa0, bv0, o[t2]);
      o[t2] = MFMA(pa1, bv1, o[t2]);
    }
    __builtin_amdgcn_s_setprio(0);

    __syncthreads();
    cur ^= 1;
  }

#pragma unroll
  for (int r = 0; r < 4; ++r) {
    float lr = __shfl(lR, g4 + r);
    float invl = 1.0f / lr;
    int q = q0 + w*16 + g4 + r;
    size_t base = ((size_t)(b*NSEQ + q))*DMODEL + h*DHD;
#pragma unroll
    for (int t2 = 0; t2 < 4; ++t2)
      O[base + t2*16 + i16] = (f16)(o[t2][r] * invl);
  }
}

extern "C" void kernel_launch(void* const* d_in, const int* in_sizes, int n_in,
                              void* d_out, int out_size, void* d_ws, size_t ws_size,
                              hipStream_t stream) {
  const float* hs = (const float*)d_in[0];
  const int*   pos = (const int*)d_in[1];
  const float* Wq = (const float*)d_in[2];
  const float* Wk = (const float*)d_in[3];
  const float* Wv = (const float*)d_in[4];
  const float* Wo = (const float*)d_in[5];
  const float* qs = (const float*)d_in[6];
  const float* ks = (const float*)d_in[7];

  const int nhs = 8192*768;       // 6291456
  const int nw  = 768*768;        // 589824

  char* p = (char*)d_ws;
  f16* Xf   = (f16*)p; p += (size_t)nhs*2;
  f16* Wf   = (f16*)p; p += (size_t)3*nw*2;         // Wq|Wk|Wv
  f16* Wof  = (f16*)p; p += (size_t)nw*2;
  f16* QKpk = (f16*)p; p += (size_t)2*ROWS_PER*64*2;
  f16* Vt   = (f16*)p; p += (size_t)ROWS_PER*64*2;
  f16* Ob   = (f16*)p; p += (size_t)nhs*2;

  cast_kernel<<<nhs/1024, 256, 0, stream>>>(hs, Xf, nhs);
  cast_w_kernel<<<(4*nw)/1024, 256, 0, stream>>>(Wq, Wk, Wv, Wo, Wf, Wof, nw);

  gemm_bt<1><<<1152, 256, 0, stream>>>(Xf, Wf, nullptr, QKpk, Vt,
                                       pos, qs, ks, 8192, 2304, 768);
  attn_kernel<<<dim3(16, 96), 256, 0, stream>>>(QKpk, Vt, Ob);
  gemm_bt<0><<<384, 256, 0, stream>>>(Ob, Wof, (float*)d_out, nullptr, nullptr,
                                      nullptr, nullptr, nullptr, 8192, 768, 768);
}

// Round 8
// 140.961 us; speedup vs baseline: 2.5129x; 1.0191x over previous
//
#include <hip/hip_runtime.h>

typedef _Float16 f16;
typedef __attribute__((ext_vector_type(8))) _Float16 f16x8;
typedef __attribute__((ext_vector_type(4))) _Float16 f16x4;
typedef __attribute__((ext_vector_type(4))) float f32x4;

#define NH 12
#define DHD 64
#define NB 8
#define NSEQ 1024
#define DMODEL 768
#define BHN (NB*NH)            // 96
#define ROWS_PER (BHN*NSEQ)    // 98304

#define MFMA(a,b,c) __builtin_amdgcn_mfma_f32_16x16x32_f16(a,b,c,0,0,0)

__device__ __forceinline__ void gload16(const void* g, void* l) {
  __builtin_amdgcn_global_load_lds(
      (__attribute__((address_space(1))) void*)(g),
      (__attribute__((address_space(3))) void*)(l), 16, 0, 0);
}

__global__ __launch_bounds__(256) void cast_kernel(const float* __restrict__ in,
                                                   f16* __restrict__ out, int n) {
  int i = (blockIdx.x * blockDim.x + threadIdx.x) * 4;
  if (i < n) {
    float4 v = *(const float4*)(in + i);
    f16x4 o = {(f16)v.x, (f16)v.y, (f16)v.z, (f16)v.w};
    *(f16x4*)(out + i) = o;
  }
}

// fused cast of all four weight matrices + rope cos/sin table build (block 0)
__global__ __launch_bounds__(256) void cast_w_kernel(const float* __restrict__ Wq,
                                                     const float* __restrict__ Wk,
                                                     const float* __restrict__ Wv,
                                                     const float* __restrict__ Wo,
                                                     f16* __restrict__ Wf,
                                                     f16* __restrict__ Wof,
                                                     float2* __restrict__ rtab, int nw) {
  int i = (blockIdx.x * blockDim.x + threadIdx.x) * 4;
  if (i < 4*nw) {
    int which = i / nw;
    int off = i - which*nw;
    const float* src = (which == 0) ? Wq : (which == 1) ? Wk : (which == 2) ? Wv : Wo;
    f16* dst = (which < 3) ? (Wf + (size_t)which*nw + off) : (Wof + off);
    float4 v = *(const float4*)(src + off);
    f16x4 o = {(f16)v.x, (f16)v.y, (f16)v.z, (f16)v.w};
    *(f16x4*)dst = o;
  }
  if (blockIdx.x == 0) {
    // rope table: pos in [0,32), idx in [0,16): (cos, sin)(pos * 100^(-idx/16))
    for (int e = threadIdx.x; e < 512; e += 256) {
      int pos = e >> 4, k = e & 15;
      float ang = (float)pos * __expf((float)k * (-4.605170185988091f / 16.0f));
      float sn, cs;
      __sincosf(ang, &sn, &cs);
      rtab[e] = make_float2(cs, sn);
    }
  }
}

// C = A(MxK) * B(NxK)^T, fp16 inputs, BK=64, XOR-swizzled LDS.
// MODE 0: 128x64 tile (grid 768 = 64x12), fp32 row-major C
// MODE 1: 128x128 tile (grid 1152 = 18x64). bx<12 (Q,K): fused rms-norm+scale
//         +rope (table) -> fp16 rows [qk][bh][ns][64]. bx>=12 (V): fused
//         rms-norm + LDS transpose -> Vout [bh][64][1024] fp16.
template<int MODE>
__global__ __launch_bounds__(256) void gemm_bt(const f16* __restrict__ A,
                                               const f16* __restrict__ B,
                                               float* __restrict__ Cout,
                                               f16* __restrict__ QKout,
                                               f16* __restrict__ Vout,
                                               const int* __restrict__ pos_ids,
                                               const float* __restrict__ q_scale,
                                               const float* __restrict__ k_scale,
                                               const float2* __restrict__ rtab,
                                               int M, int N, int K) {
  constexpr int BN = (MODE == 1) ? 128 : 64;
  constexpr int NJ = BN / 32;                 // B-fragments per wave: 4 or 2
  constexpr int SHSZ = (MODE == 1) ? 17408 : (8192 + 4096);
  __shared__ __align__(16) f16 SH[SHSZ];
  f16* Ash = SH;
  f16* Bsh = SH + 8192;
  const int tid = threadIdx.x;
  const int w = tid >> 6, l = tid & 63;
  const int wr = w >> 1, wc = w & 1;
  const int g = l >> 4, i16 = l & 15;

  // XCD-aware bijective swizzle (grid%8==0 in both modes)
  int bx, by;
  {
    int id = blockIdx.x;
    const int nbx = (MODE == 1) ? 18 : 12;
    const int chunk = (MODE == 1) ? 144 : 96;
    int idp = (id & 7) * chunk + (id >> 3);
    by = idp / nbx; bx = idp - by * nbx;
  }
  const bool isV = (MODE == 1) && (bx >= 12);

  const f32x4 fzero = {0.f, 0.f, 0.f, 0.f};
  f32x4 acc[4][NJ];
#pragma unroll
  for (int i = 0; i < 4; i++)
#pragma unroll
    for (int j = 0; j < NJ; j++) acc[i][j] = fzero;

  // staging: issue n covers rows n*32+(tid>>3); source chunk pre-swizzled by row&7
  const int srow = tid >> 3;
  const int schunk = (tid & 7) ^ (srow & 7);
  const size_t arow = (size_t)(by*128 + srow)*K + schunk*8;
  const size_t brow = (size_t)(bx*BN + srow)*K + schunk*8;
  char* AlB = (char*)Ash + w*1024;
  char* BlB = (char*)Bsh + w*1024;

  for (int k0 = 0; k0 < K; k0 += 64) {
    __syncthreads();
#pragma unroll
    for (int n = 0; n < 4; ++n)
      gload16(A + arow + (size_t)(n*32)*K + k0, AlB + n*4096);
#pragma unroll
    for (int n = 0; n < BN/32; ++n)
      gload16(B + brow + (size_t)(n*32)*K + k0, BlB + n*4096);
    __syncthreads();
#pragma unroll
    for (int kk = 0; kk < 2; ++kk) {
      f16x8 af[4], bfr[NJ];
#pragma unroll
      for (int i = 0; i < 4; i++)
        af[i] = *(const f16x8*)(Ash + (wr*64 + i*16 + i16)*64 + ((kk*4 + g) ^ (i16 & 7))*8);
#pragma unroll
      for (int j = 0; j < NJ; j++)
        bfr[j] = *(const f16x8*)(Bsh + (wc*(BN/2) + j*16 + i16)*64 + ((kk*4 + g) ^ (i16 & 7))*8);
#pragma unroll
      for (int i = 0; i < 4; i++)
#pragma unroll
        for (int j = 0; j < NJ; j++)
          acc[i][j] = MFMA(af[i], bfr[j], acc[i][j]);
    }
  }

  const int m0 = by*128 + wr*64;
  const int n0 = bx*BN + wc*(BN/2);
  if (MODE == 0) {
#pragma unroll
    for (int i = 0; i < 4; i++)
#pragma unroll
      for (int j = 0; j < NJ; j++)
#pragma unroll
        for (int r = 0; r < 4; r++) {
          int m = m0 + i*16 + g*4 + r;
          int n = n0 + j*16 + i16;
          Cout[(size_t)m*N + n] = acc[i][j][r];
        }
  } else if (isV) {
    // V: rms-norm + LDS transpose -> Vout [bh][64][1024]
    const int h0 = (bx - 12)*2;
    const int bb = by >> 3;
    const int ns0 = (by & 7) * 128;
    f16* Lt = SH;                       // [128 dh][136]
    __syncthreads();                    // all waves done with staging LDS
#pragma unroll
    for (int i = 0; i < 4; i++) {
      f32x4 ssv = fzero;
#pragma unroll
      for (int j = 0; j < 4; j++)
#pragma unroll
        for (int r = 0; r < 4; r++) ssv[r] += acc[i][j][r]*acc[i][j][r];
#pragma unroll
      for (int d = 1; d < 16; d <<= 1)
#pragma unroll
        for (int r = 0; r < 4; r++) ssv[r] += __shfl_xor(ssv[r], d);
#pragma unroll
      for (int r = 0; r < 4; r++) {
        float rinv = rsqrtf(ssv[r] * (1.0f/64.0f) + 1e-6f);
        int nsl = wr*64 + i*16 + g*4 + r;
#pragma unroll
        for (int j = 0; j < 4; j++)
          Lt[(wc*64 + j*16 + i16)*136 + nsl] = (f16)(acc[i][j][r]*rinv);
      }
    }
    __syncthreads();
    const int dh = tid >> 1, half = tid & 1;
    f16* dst = Vout + ((size_t)((bb*NH + h0 + (dh >> 6))*64 + (dh & 63)))*1024
               + ns0 + half*64;
    const f16* ls = Lt + dh*136 + half*64;
#pragma unroll
    for (int e = 0; e < 8; ++e)
      *(uint4*)(dst + e*8) = *(const uint4*)(ls + e*8);
  } else {
    // fused rms-norm + scale + 2D rope (table-driven) for Q/K, fp16 out
    const int qkv = n0 / DMODEL;
    const int h = (n0 - qkv*DMODEL) >> 6;
    const float* scp = (qkv == 0) ? q_scale : k_scale;
    float scl[4];
#pragma unroll
    for (int j = 0; j < 4; j++) scl[j] = scp[j*16 + i16];
    const float2* rt = rtab + i16;      // row: pos*16 + i16
#pragma unroll
    for (int i = 0; i < 4; i++) {
      f32x4 ssv = fzero;
#pragma unroll
      for (int j = 0; j < 4; j++)
#pragma unroll
        for (int r = 0; r < 4; r++) ssv[r] += acc[i][j][r]*acc[i][j][r];
#pragma unroll
      for (int d = 1; d < 16; d <<= 1)
#pragma unroll
        for (int r = 0; r < 4; r++) ssv[r] += __shfl_xor(ssv[r], d);
#pragma unroll
      for (int r = 0; r < 4; r++) {
        int m = m0 + i*16 + g*4 + r;
        int bb = m >> 10, ns = m & 1023;
        float rinv = rsqrtf(ssv[r] * (1.0f/64.0f) + 1e-6f);
        int2 pp = *(const int2*)(pos_ids + ((size_t)bb*NSEQ + ns)*2);
        float2 t0 = rt[pp.x*16];
        float2 t1 = rt[pp.y*16];
        float x0 = acc[i][0][r]*rinv*scl[0];
        float x1 = acc[i][1][r]*rinv*scl[1];
        float x2 = acc[i][2][r]*rinv*scl[2];
        float x3 = acc[i][3][r]*rinv*scl[3];
        size_t row = ((size_t)qkv*BHN + bb*NH + h)*NSEQ + ns;
        f16* ob = QKout + row*64;
        ob[i16]      = (f16)(x0*t0.x - x1*t0.y);
        ob[16 + i16] = (f16)(x1*t0.x + x0*t0.y);
        ob[32 + i16] = (f16)(x2*t1.x - x3*t1.y);
        ob[48 + i16] = (f16)(x3*t1.x + x2*t1.y);
      }
    }
  }
}

// sigma: LDS K-row p holds physical kv sigma(p); bit layout p={u,b,g,g,c,c} -> {u,g,g,b,c,c}
__device__ __forceinline__ int sigma_perm(int p) {
  return (p & 0x20) | ((p & 0xC) << 1) | ((p & 0x10) >> 2) | (p & 3);
}

// flash attention: grid (16 qblocks, 96 bh), 4 waves x 16 q rows, KV tile = 64
// swapped QK^T (K as A-operand) + sigma-permuted K staging => P stays in registers.
__global__ __launch_bounds__(256) void attn_kernel(const f16* __restrict__ QKu,
                                                   const f16* __restrict__ Vtu,
                                                   f16* __restrict__ O) {
  const int bh = blockIdx.y;
  const int q0 = blockIdx.x * 64;
  const int tid = threadIdx.x, w = tid >> 6, l = tid & 63;
  const int g = l >> 4, i16 = l & 15;
  const int g4 = g*4;
  const int sw = i16 & 7;
  const int b = bh / NH, h = bh - b*NH;

  __shared__ __align__(16) f16 Ks[2*64*64];
  __shared__ __align__(16) f16 Vs[2*64*64];

  const f16* qrow = QKu + ((size_t)bh*NSEQ + q0 + w*16 + i16)*64;
  f16x8 q0f = *(const f16x8*)(qrow + g*8);
  f16x8 q1f = *(const f16x8*)(qrow + 32 + g*8);

  const char* Kb  = (const char*)(QKu + (size_t)(BHN + bh)*NSEQ*64);
  const char* Vtb = (const char*)(Vtu + (size_t)bh*64*1024);
  const int prow0 = w*8 + (l >> 3);
  const int cl = (l & 7) ^ (l >> 3);
  const char* Ksrc0 = Kb + sigma_perm(prow0)*128 + cl*16;
  const char* Ksrc1 = Kb + (sigma_perm(prow0) + 32)*128 + cl*16;
  const char* Vsrc0 = Vtb + prow0*2048 + cl*16;
  const char* Vsrc1 = Vtb + (prow0 + 32)*2048 + cl*16;

  const f32x4 fzero = {0.f, 0.f, 0.f, 0.f};
  float mR = -1e30f, lR = 0.f;
  f32x4 o[4];
#pragma unroll
  for (int t = 0; t < 4; t++) o[t] = fzero;

  int cur = 0;
  {
    char* kd = (char*)Ks + w*1024;
    char* vd = (char*)Vs + w*1024;
    gload16(Ksrc0, kd);
    gload16(Ksrc1, kd + 4096);
    gload16(Vsrc0, vd);
    gload16(Vsrc1, vd + 4096);
  }
  __syncthreads();

  for (int t = 0; t < 16; ++t) {
    if (t < 15) {
      char* kd = (char*)Ks + (cur^1)*8192 + w*1024;
      char* vd = (char*)Vs + (cur^1)*8192 + w*1024;
      gload16(Ksrc0 + (t+1)*8192, kd);
      gload16(Ksrc1 + (t+1)*8192, kd + 4096);
      gload16(Vsrc0 + (t+1)*128,  vd);
      gload16(Vsrc1 + (t+1)*128,  vd + 4096);
    }
    const f16* Kc = Ks + cur*4096;
    const f16* Vc = Vs + cur*4096;

    f32x4 s[4] = {fzero, fzero, fzero, fzero};
    __builtin_amdgcn_s_setprio(1);
#pragma unroll
    for (int j = 0; j < 4; ++j) {
      const f16* kr = Kc + (j*16 + i16)*64;
      f16x8 k0 = *(const f16x8*)(kr + (g ^ sw)*8);
      f16x8 k1 = *(const f16x8*)(kr + ((g^4) ^ sw)*8);
      s[j] = MFMA(k0, q0f, s[j]);
      s[j] = MFMA(k1, q1f, s[j]);
    }
    __builtin_amdgcn_s_setprio(0);

    float tm = fmaxf(
        fmaxf(fmaxf(fmaxf(s[0][0],s[0][1]), fmaxf(s[0][2],s[0][3])),
              fmaxf(fmaxf(s[1][0],s[1][1]), fmaxf(s[1][2],s[1][3]))),
        fmaxf(fmaxf(fmaxf(s[2][0],s[2][1]), fmaxf(s[2][2],s[2][3])),
              fmaxf(fmaxf(s[3][0],s[3][1]), fmaxf(s[3][2],s[3][3]))));
    tm = fmaxf(tm, __shfl_xor(tm, 16));
    tm = fmaxf(tm, __shfl_xor(tm, 32));
    if (__any(tm > mR + 8.0f)) {
      float nm = fmaxf(mR, tm);
      float fac = __expf(mR - nm);
      mR = nm;
      lR *= fac;
#pragma unroll
      for (int r = 0; r < 4; ++r) {
        float fr = __shfl(fac, g4 + r);
        o[0][r] *= fr; o[1][r] *= fr; o[2][r] *= fr; o[3][r] *= fr;
      }
    }
    float rs = 0.f;
#pragma unroll
    for (int j = 0; j < 4; ++j)
#pragma unroll
      for (int r = 0; r < 4; ++r) { s[j][r] = __expf(s[j][r] - mR); rs += s[j][r]; }
    rs += __shfl_xor(rs, 16);
    rs += __shfl_xor(rs, 32);
    lR += rs;

    f16x8 pa0, pa1;
#pragma unroll
    for (int e = 0; e < 4; ++e) {
      pa0[e]   = (f16)s[0][e];
      pa0[4+e] = (f16)s[1][e];
      pa1[e]   = (f16)s[2][e];
      pa1[4+e] = (f16)s[3][e];
    }
    __builtin_amdgcn_s_setprio(1);
#pragma unroll
    for (int t2 = 0; t2 < 4; ++t2) {
      const f16* vr = Vc + (t2*16 + i16)*64;
      f16x8 bv0 = *(const f16x8*)(vr + (g ^ sw)*8);
      f16x8 bv1 = *(const f16x8*)(vr + ((g^4) ^ sw)*8);
      o[t2] = MFMA(pa0, bv0, o[t2]);
      o[t2] = MFMA(pa1, bv1, o[t2]);
    }
    __builtin_amdgcn_s_setprio(0);

    __syncthreads();
    cur ^= 1;
  }

#pragma unroll
  for (int r = 0; r < 4; ++r) {
    float lr = __shfl(lR, g4 + r);
    float invl = 1.0f / lr;
    int q = q0 + w*16 + g4 + r;
    size_t base = ((size_t)(b*NSEQ + q))*DMODEL + h*DHD;
#pragma unroll
    for (int t2 = 0; t2 < 4; ++t2)
      O[base + t2*16 + i16] = (f16)(o[t2][r] * invl);
  }
}

extern "C" void kernel_launch(void* const* d_in, const int* in_sizes, int n_in,
                              void* d_out, int out_size, void* d_ws, size_t ws_size,
                              hipStream_t stream) {
  const float* hs = (const float*)d_in[0];
  const int*   pos = (const int*)d_in[1];
  const float* Wq = (const float*)d_in[2];
  const float* Wk = (const float*)d_in[3];
  const float* Wv = (const float*)d_in[4];
  const float* Wo = (const float*)d_in[5];
  const float* qs = (const float*)d_in[6];
  const float* ks = (const float*)d_in[7];

  const int nhs = 8192*768;       // 6291456
  const int nw  = 768*768;        // 589824

  char* p = (char*)d_ws;
  f16* Xf   = (f16*)p; p += (size_t)nhs*2;
  f16* Wf   = (f16*)p; p += (size_t)3*nw*2;         // Wq|Wk|Wv
  f16* Wof  = (f16*)p; p += (size_t)nw*2;
  f16* QKpk = (f16*)p; p += (size_t)2*ROWS_PER*64*2;
  f16* Vt   = (f16*)p; p += (size_t)ROWS_PER*64*2;
  f16* Ob   = (f16*)p; p += (size_t)nhs*2;
  float2* Rtab = (float2*)p; p += 512*sizeof(float2);

  cast_kernel<<<nhs/1024, 256, 0, stream>>>(hs, Xf, nhs);
  cast_w_kernel<<<(4*nw)/1024, 256, 0, stream>>>(Wq, Wk, Wv, Wo, Wf, Wof, Rtab, nw);

  gemm_bt<1><<<1152, 256, 0, stream>>>(Xf, Wf, nullptr, QKpk, Vt,
                                       pos, qs, ks, Rtab, 8192, 2304, 768);
  attn_kernel<<<dim3(16, 96), 256, 0, stream>>>(QKpk, Vt, Ob);
  gemm_bt<0><<<768, 256, 0, stream>>>(Ob, Wof, (float*)d_out, nullptr, nullptr,
                                      nullptr, nullptr, nullptr, nullptr, 8192, 768, 768);
}

// Round 9
// 136.361 us; speedup vs baseline: 2.5977x; 1.0337x over previous
//
#include <hip/hip_runtime.h>

typedef _Float16 f16;
typedef __attribute__((ext_vector_type(8))) _Float16 f16x8;
typedef __attribute__((ext_vector_type(4))) _Float16 f16x4;
typedef __attribute__((ext_vector_type(4))) float f32x4;

#define NH 12
#define DHD 64
#define NB 8
#define NSEQ 1024
#define DMODEL 768
#define BHN (NB*NH)            // 96
#define ROWS_PER (BHN*NSEQ)    // 98304

#define MFMA(a,b,c) __builtin_amdgcn_mfma_f32_16x16x32_f16(a,b,c,0,0,0)

__device__ __forceinline__ void gload16(const void* g, void* l) {
  __builtin_amdgcn_global_load_lds(
      (__attribute__((address_space(1))) void*)(g),
      (__attribute__((address_space(3))) void*)(l), 16, 0, 0);
}

__global__ __launch_bounds__(256) void cast_kernel(const float* __restrict__ in,
                                                   f16* __restrict__ out, int n) {
  int i = (blockIdx.x * blockDim.x + threadIdx.x) * 4;
  if (i < n) {
    float4 v = *(const float4*)(in + i);
    f16x4 o = {(f16)v.x, (f16)v.y, (f16)v.z, (f16)v.w};
    *(f16x4*)(out + i) = o;
  }
}

// fused cast of all four weight matrices + rope cos/sin table build (block 0)
__global__ __launch_bounds__(256) void cast_w_kernel(const float* __restrict__ Wq,
                                                     const float* __restrict__ Wk,
                                                     const float* __restrict__ Wv,
                                                     const float* __restrict__ Wo,
                                                     f16* __restrict__ Wf,
                                                     f16* __restrict__ Wof,
                                                     float2* __restrict__ rtab, int nw) {
  int i = (blockIdx.x * blockDim.x + threadIdx.x) * 4;
  if (i < 4*nw) {
    int which = i / nw;
    int off = i - which*nw;
    const float* src = (which == 0) ? Wq : (which == 1) ? Wk : (which == 2) ? Wv : Wo;
    f16* dst = (which < 3) ? (Wf + (size_t)which*nw + off) : (Wof + off);
    float4 v = *(const float4*)(src + off);
    f16x4 o = {(f16)v.x, (f16)v.y, (f16)v.z, (f16)v.w};
    *(f16x4*)dst = o;
  }
  if (blockIdx.x == 0) {
    for (int e = threadIdx.x; e < 512; e += 256) {
      int pos = e >> 4, k = e & 15;
      float ang = (float)pos * __expf((float)k * (-4.605170185988091f / 16.0f));
      float sn, cs;
      __sincosf(ang, &sn, &cs);
      rtab[e] = make_float2(cs, sn);
    }
  }
}

// C = A(MxK) * B(NxK)^T, fp16 inputs, BK=64, XOR-swizzled, DOUBLE-BUFFERED LDS
// (prefetch tile t+1 before compute of t; one barrier per K-step).
// MODE 0: 128x64 tile (grid 768 = 64x12), fp32 row-major C
// MODE 1: 128x128 tile (grid 1152 = 18x64). bx<12 (Q,K): fused rms-norm+scale
//         +rope (table) -> fp16 rows [qk][bh][ns][64]. bx>=12 (V): fused
//         rms-norm + LDS transpose -> Vout [bh][64][1024] fp16.
template<int MODE>
__global__ __launch_bounds__(256) void gemm_bt(const f16* __restrict__ A,
                                               const f16* __restrict__ B,
                                               float* __restrict__ Cout,
                                               f16* __restrict__ QKout,
                                               f16* __restrict__ Vout,
                                               const int* __restrict__ pos_ids,
                                               const float* __restrict__ q_scale,
                                               const float* __restrict__ k_scale,
                                               const float2* __restrict__ rtab,
                                               int M, int N, int K) {
  constexpr int BN = (MODE == 1) ? 128 : 64;
  constexpr int NJ = BN / 32;                 // B-fragments per wave: 4 or 2
  constexpr int ABUF = 8192;                  // f16 per A buffer (128x64)
  constexpr int BBUF = BN*64;                 // f16 per B buffer
  __shared__ __align__(16) f16 SH[2*ABUF + 2*BBUF];   // MODE1: 64KB, MODE0: 48KB
  const int tid = threadIdx.x;
  const int w = tid >> 6, l = tid & 63;
  const int wr = w >> 1, wc = w & 1;
  const int g = l >> 4, i16 = l & 15;

  // XCD-aware bijective swizzle (grid%8==0 in both modes)
  int bx, by;
  {
    int id = blockIdx.x;
    const int nbx = (MODE == 1) ? 18 : 12;
    const int chunk = (MODE == 1) ? 144 : 96;
    int idp = (id & 7) * chunk + (id >> 3);
    by = idp / nbx; bx = idp - by * nbx;
  }
  const bool isV = (MODE == 1) && (bx >= 12);

  const f32x4 fzero = {0.f, 0.f, 0.f, 0.f};
  f32x4 acc[4][NJ];
#pragma unroll
  for (int i = 0; i < 4; i++)
#pragma unroll
    for (int j = 0; j < NJ; j++) acc[i][j] = fzero;

  // staging: issue n covers rows n*32+(tid>>3); source chunk pre-swizzled by row&7
  const int srow = tid >> 3;
  const int schunk = (tid & 7) ^ (srow & 7);
  const size_t arow = (size_t)(by*128 + srow)*K + schunk*8;
  const size_t brow = (size_t)(bx*BN + srow)*K + schunk*8;

  const int nt = K / 64;  // 12
#define STAGE(buf, k0)                                                          \
  {                                                                             \
    char* AlB = (char*)(SH + (buf)*ABUF) + w*1024;                              \
    char* BlB = (char*)(SH + 2*ABUF + (buf)*BBUF) + w*1024;                     \
    _Pragma("unroll")                                                           \
    for (int n = 0; n < 4; ++n)                                                 \
      gload16(A + arow + (size_t)(n*32)*K + (k0), AlB + n*4096);                \
    _Pragma("unroll")                                                           \
    for (int n = 0; n < BN/32; ++n)                                             \
      gload16(B + brow + (size_t)(n*32)*K + (k0), BlB + n*4096);                \
  }

  STAGE(0, 0);
  __syncthreads();
  for (int t = 0; t < nt; ++t) {
    const int buf = t & 1;
    if (t + 1 < nt) STAGE(buf ^ 1, (t + 1)*64);
    const f16* Ac = SH + buf*ABUF;
    const f16* Bc = SH + 2*ABUF + buf*BBUF;
#pragma unroll
    for (int kk = 0; kk < 2; ++kk) {
      f16x8 af[4], bfr[NJ];
#pragma unroll
      for (int i = 0; i < 4; i++)
        af[i] = *(const f16x8*)(Ac + (wr*64 + i*16 + i16)*64 + ((kk*4 + g) ^ (i16 & 7))*8);
#pragma unroll
      for (int j = 0; j < NJ; j++)
        bfr[j] = *(const f16x8*)(Bc + (wc*(BN/2) + j*16 + i16)*64 + ((kk*4 + g) ^ (i16 & 7))*8);
#pragma unroll
      for (int i = 0; i < 4; i++)
#pragma unroll
        for (int j = 0; j < NJ; j++)
          acc[i][j] = MFMA(af[i], bfr[j], acc[i][j]);
    }
    __syncthreads();
  }
#undef STAGE

  const int m0 = by*128 + wr*64;
  const int n0 = bx*BN + wc*(BN/2);
  if (MODE == 0) {
#pragma unroll
    for (int i = 0; i < 4; i++)
#pragma unroll
      for (int j = 0; j < NJ; j++)
#pragma unroll
        for (int r = 0; r < 4; r++) {
          int m = m0 + i*16 + g*4 + r;
          int n = n0 + j*16 + i16;
          Cout[(size_t)m*N + n] = acc[i][j][r];
        }
  } else if (isV) {
    // V: rms-norm + LDS transpose -> Vout [bh][64][1024]
    const int h0 = (bx - 12)*2;
    const int bb = by >> 3;
    const int ns0 = (by & 7) * 128;
    f16* Lt = SH;                       // [128 dh][136] = 17408 f16 <= 32768
#pragma unroll
    for (int i = 0; i < 4; i++) {
      f32x4 ssv = fzero;
#pragma unroll
      for (int j = 0; j < 4; j++)
#pragma unroll
        for (int r = 0; r < 4; r++) ssv[r] += acc[i][j][r]*acc[i][j][r];
#pragma unroll
      for (int d = 1; d < 16; d <<= 1)
#pragma unroll
        for (int r = 0; r < 4; r++) ssv[r] += __shfl_xor(ssv[r], d);
#pragma unroll
      for (int r = 0; r < 4; r++) {
        float rinv = rsqrtf(ssv[r] * (1.0f/64.0f) + 1e-6f);
        int nsl = wr*64 + i*16 + g*4 + r;
#pragma unroll
        for (int j = 0; j < 4; j++)
          Lt[(wc*64 + j*16 + i16)*136 + nsl] = (f16)(acc[i][j][r]*rinv);
      }
    }
    __syncthreads();
    const int dh = tid >> 1, half = tid & 1;
    f16* dst = Vout + ((size_t)((bb*NH + h0 + (dh >> 6))*64 + (dh & 63)))*1024
               + ns0 + half*64;
    const f16* ls = Lt + dh*136 + half*64;
#pragma unroll
    for (int e = 0; e < 8; ++e)
      *(uint4*)(dst + e*8) = *(const uint4*)(ls + e*8);
  } else {
    // fused rms-norm + scale + 2D rope (table-driven) for Q/K, fp16 out
    const int qkv = n0 / DMODEL;
    const int h = (n0 - qkv*DMODEL) >> 6;
    const float* scp = (qkv == 0) ? q_scale : k_scale;
    float scl[4];
#pragma unroll
    for (int j = 0; j < 4; j++) scl[j] = scp[j*16 + i16];
    const float2* rt = rtab + i16;      // row: pos*16 + i16
#pragma unroll
    for (int i = 0; i < 4; i++) {
      f32x4 ssv = fzero;
#pragma unroll
      for (int j = 0; j < 4; j++)
#pragma unroll
        for (int r = 0; r < 4; r++) ssv[r] += acc[i][j][r]*acc[i][j][r];
#pragma unroll
      for (int d = 1; d < 16; d <<= 1)
#pragma unroll
        for (int r = 0; r < 4; r++) ssv[r] += __shfl_xor(ssv[r], d);
#pragma unroll
      for (int r = 0; r < 4; r++) {
        int m = m0 + i*16 + g*4 + r;
        int bb = m >> 10, ns = m & 1023;
        float rinv = rsqrtf(ssv[r] * (1.0f/64.0f) + 1e-6f);
        int2 pp = *(const int2*)(pos_ids + ((size_t)bb*NSEQ + ns)*2);
        float2 t0 = rt[pp.x*16];
        float2 t1 = rt[pp.y*16];
        float x0 = acc[i][0][r]*rinv*scl[0];
        float x1 = acc[i][1][r]*rinv*scl[1];
        float x2 = acc[i][2][r]*rinv*scl[2];
        float x3 = acc[i][3][r]*rinv*scl[3];
        size_t row = ((size_t)qkv*BHN + bb*NH + h)*NSEQ + ns;
        f16* ob = QKout + row*64;
        ob[i16]      = (f16)(x0*t0.x - x1*t0.y);
        ob[16 + i16] = (f16)(x1*t0.x + x0*t0.y);
        ob[32 + i16] = (f16)(x2*t1.x - x3*t1.y);
        ob[48 + i16] = (f16)(x3*t1.x + x2*t1.y);
      }
    }
  }
}

// sigma: LDS K-row p holds physical kv sigma(p); bit layout p={u,b,g,g,c,c} -> {u,g,g,b,c,c}
__device__ __forceinline__ int sigma_perm(int p) {
  return (p & 0x20) | ((p & 0xC) << 1) | ((p & 0x10) >> 2) | (p & 3);
}

// flash attention: grid (16 qblocks, 96 bh), 4 waves x 16 q rows, KV tile = 64
// swapped QK^T (K as A-operand) + sigma-permuted K staging => P stays in registers.
__global__ __launch_bounds__(256) void attn_kernel(const f16* __restrict__ QKu,
                                                   const f16* __restrict__ Vtu,
                                                   f16* __restrict__ O) {
  const int bh = blockIdx.y;
  const int q0 = blockIdx.x * 64;
  const int tid = threadIdx.x, w = tid >> 6, l = tid & 63;
  const int g = l >> 4, i16 = l & 15;
  const int g4 = g*4;
  const int sw = i16 & 7;
  const int b = bh / NH, h = bh - b*NH;

  __shared__ __align__(16) f16 Ks[2*64*64];
  __shared__ __align__(16) f16 Vs[2*64*64];

  const f16* qrow = QKu + ((size_t)bh*NSEQ + q0 + w*16 + i16)*64;
  f16x8 q0f = *(const f16x8*)(qrow + g*8);
  f16x8 q1f = *(const f16x8*)(qrow + 32 + g*8);

  const char* Kb  = (const char*)(QKu + (size_t)(BHN + bh)*NSEQ*64);
  const char* Vtb = (const char*)(Vtu + (size_t)bh*64*1024);
  const int prow0 = w*8 + (l >> 3);
  const int cl = (l & 7) ^ (l >> 3);
  const char* Ksrc0 = Kb + sigma_perm(prow0)*128 + cl*16;
  const char* Ksrc1 = Kb + (sigma_perm(prow0) + 32)*128 + cl*16;
  const char* Vsrc0 = Vtb + prow0*2048 + cl*16;
  const char* Vsrc1 = Vtb + (prow0 + 32)*2048 + cl*16;

  const f32x4 fzero = {0.f, 0.f, 0.f, 0.f};
  float mR = -1e30f, lR = 0.f;
  f32x4 o[4];
#pragma unroll
  for (int t = 0; t < 4; t++) o[t] = fzero;

  int cur = 0;
  {
    char* kd = (char*)Ks + w*1024;
    char* vd = (char*)Vs + w*1024;
    gload16(Ksrc0, kd);
    gload16(Ksrc1, kd + 4096);
    gload16(Vsrc0, vd);
    gload16(Vsrc1, vd + 4096);
  }
  __syncthreads();

  for (int t = 0; t < 16; ++t) {
    if (t < 15) {
      char* kd = (char*)Ks + (cur^1)*8192 + w*1024;
      char* vd = (char*)Vs + (cur^1)*8192 + w*1024;
      gload16(Ksrc0 + (t+1)*8192, kd);
      gload16(Ksrc1 + (t+1)*8192, kd + 4096);
      gload16(Vsrc0 + (t+1)*128,  vd);
      gload16(Vsrc1 + (t+1)*128,  vd + 4096);
    }
    const f16* Kc = Ks + cur*4096;
    const f16* Vc = Vs + cur*4096;

    f32x4 s[4] = {fzero, fzero, fzero, fzero};
    __builtin_amdgcn_s_setprio(1);
#pragma unroll
    for (int j = 0; j < 4; ++j) {
      const f16* kr = Kc + (j*16 + i16)*64;
      f16x8 k0 = *(const f16x8*)(kr + (g ^ sw)*8);
      f16x8 k1 = *(const f16x8*)(kr + ((g^4) ^ sw)*8);
      s[j] = MFMA(k0, q0f, s[j]);
      s[j] = MFMA(k1, q1f, s[j]);
    }
    __builtin_amdgcn_s_setprio(0);

    float tm = fmaxf(
        fmaxf(fmaxf(fmaxf(s[0][0],s[0][1]), fmaxf(s[0][2],s[0][3])),
              fmaxf(fmaxf(s[1][0],s[1][1]), fmaxf(s[1][2],s[1][3]))),
        fmaxf(fmaxf(fmaxf(s[2][0],s[2][1]), fmaxf(s[2][2],s[2][3])),
              fmaxf(fmaxf(s[3][0],s[3][1]), fmaxf(s[3][2],s[3][3]))));
    tm = fmaxf(tm, __shfl_xor(tm, 16));
    tm = fmaxf(tm, __shfl_xor(tm, 32));
    if (__any(tm > mR + 8.0f)) {
      float nm = fmaxf(mR, tm);
      float fac = __expf(mR - nm);
      mR = nm;
      lR *= fac;
#pragma unroll
      for (int r = 0; r < 4; ++r) {
        float fr = __shfl(fac, g4 + r);
        o[0][r] *= fr; o[1][r] *= fr; o[2][r] *= fr; o[3][r] *= fr;
      }
    }
    float rs = 0.f;
#pragma unroll
    for (int j = 0; j < 4; ++j)
#pragma unroll
      for (int r = 0; r < 4; ++r) { s[j][r] = __expf(s[j][r] - mR); rs += s[j][r]; }
    rs += __shfl_xor(rs, 16);
    rs += __shfl_xor(rs, 32);
    lR += rs;

    f16x8 pa0, pa1;
#pragma unroll
    for (int e = 0; e < 4; ++e) {
      pa0[e]   = (f16)s[0][e];
      pa0[4+e] = (f16)s[1][e];
      pa1[e]   = (f16)s[2][e];
      pa1[4+e] = (f16)s[3][e];
    }
    __builtin_amdgcn_s_setprio(1);
#pragma unroll
    for (int t2 = 0; t2 < 4; ++t2) {
      const f16* vr = Vc + (t2*16 + i16)*64;
      f16x8 bv0 = *(const f16x8*)(vr + (g ^ sw)*8);
      f16x8 bv1 = *(const f16x8*)(vr + ((g^4) ^ sw)*8);
      o[t2] = MFMA(pa0, bv0, o[t2]);
      o[t2] = MFMA(pa1, bv1, o[t2]);
    }
    __builtin_amdgcn_s_setprio(0);

    __syncthreads();
    cur ^= 1;
  }

#pragma unroll
  for (int r = 0; r < 4; ++r) {
    float lr = __shfl(lR, g4 + r);
    float invl = 1.0f / lr;
    int q = q0 + w*16 + g4 + r;
    size_t base = ((size_t)(b*NSEQ + q))*DMODEL + h*DHD;
#pragma unroll
    for (int t2 = 0; t2 < 4; ++t2)
      O[base + t2*16 + i16] = (f16)(o[t2][r] * invl);
  }
}

extern "C" void kernel_launch(void* const* d_in, const int* in_sizes, int n_in,
                              void* d_out, int out_size, void* d_ws, size_t ws_size,
                              hipStream_t stream) {
  const float* hs = (const float*)d_in[0];
  const int*   pos = (const int*)d_in[1];
  const float* Wq = (const float*)d_in[2];
  const float* Wk = (const float*)d_in[3];
  const float* Wv = (const float*)d_in[4];
  const float* Wo = (const float*)d_in[5];
  const float* qs = (const float*)d_in[6];
  const float* ks = (const float*)d_in[7];

  const int nhs = 8192*768;       // 6291456
  const int nw  = 768*768;        // 589824

  char* p = (char*)d_ws;
  f16* Xf   = (f16*)p; p += (size_t)nhs*2;
  f16* Wf   = (f16*)p; p += (size_t)3*nw*2;         // Wq|Wk|Wv
  f16* Wof  = (f16*)p; p += (size_t)nw*2;
  f16* QKpk = (f16*)p; p += (size_t)2*ROWS_PER*64*2;
  f16* Vt   = (f16*)p; p += (size_t)ROWS_PER*64*2;
  f16* Ob   = (f16*)p; p += (size_t)nhs*2;
  float2* Rtab = (float2*)p; p += 512*sizeof(float2);

  cast_kernel<<<nhs/1024, 256, 0, stream>>>(hs, Xf, nhs);
  cast_w_kernel<<<(4*nw)/1024, 256, 0, stream>>>(Wq, Wk, Wv, Wo, Wf, Wof, Rtab, nw);

  gemm_bt<1><<<1152, 256, 0, stream>>>(Xf, Wf, nullptr, QKpk, Vt,
                                       pos, qs, ks, Rtab, 8192, 2304, 768);
  attn_kernel<<<dim3(16, 96), 256, 0, stream>>>(QKpk, Vt, Ob);
  gemm_bt<0><<<768, 256, 0, stream>>>(Ob, Wof, (float*)d_out, nullptr, nullptr,
                                      nullptr, nullptr, nullptr, nullptr, 8192, 768, 768);
}

// Round 11
// 131.171 us; speedup vs baseline: 2.7004x; 1.0396x over previous
//
#include <hip/hip_runtime.h>

typedef _Float16 f16;
typedef __attribute__((ext_vector_type(8))) _Float16 f16x8;
typedef __attribute__((ext_vector_type(4))) _Float16 f16x4;
typedef __attribute__((ext_vector_type(2))) __fp16 h16x2;
typedef __attribute__((ext_vector_type(4))) float f32x4;

#define NH 12
#define DHD 64
#define NB 8
#define NSEQ 1024
#define DMODEL 768
#define BHN (NB*NH)            // 96
#define ROWS_PER (BHN*NSEQ)    // 98304

#define MFMA(a,b,c) __builtin_amdgcn_mfma_f32_16x16x32_f16(a,b,c,0,0,0)

__device__ __forceinline__ void gload16(const void* g, void* l) {
  __builtin_amdgcn_global_load_lds(
      (__attribute__((address_space(1))) void*)(g),
      (__attribute__((address_space(3))) void*)(l), 16, 0, 0);
}

__global__ __launch_bounds__(256) void cast_kernel(const float* __restrict__ in,
                                                   f16* __restrict__ out, int n) {
  int i = (blockIdx.x * blockDim.x + threadIdx.x) * 4;
  if (i < n) {
    float4 v = *(const float4*)(in + i);
    f16x4 o = {(f16)v.x, (f16)v.y, (f16)v.z, (f16)v.w};
    *(f16x4*)(out + i) = o;
  }
}

// fused cast of all four weight matrices + rope cos/sin table build (block 0)
__global__ __launch_bounds__(256) void cast_w_kernel(const float* __restrict__ Wq,
                                                     const float* __restrict__ Wk,
                                                     const float* __restrict__ Wv,
                                                     const float* __restrict__ Wo,
                                                     f16* __restrict__ Wf,
                                                     f16* __restrict__ Wof,
                                                     float2* __restrict__ rtab, int nw) {
  int i = (blockIdx.x * blockDim.x + threadIdx.x) * 4;
  if (i < 4*nw) {
    int which = i / nw;
    int off = i - which*nw;
    const float* src = (which == 0) ? Wq : (which == 1) ? Wk : (which == 2) ? Wv : Wo;
    f16* dst = (which < 3) ? (Wf + (size_t)which*nw + off) : (Wof + off);
    float4 v = *(const float4*)(src + off);
    f16x4 o = {(f16)v.x, (f16)v.y, (f16)v.z, (f16)v.w};
    *(f16x4*)dst = o;
  }
  if (blockIdx.x == 0) {
    for (int e = threadIdx.x; e < 512; e += 256) {
      int pos = e >> 4, k = e & 15;
      float ang = (float)pos * __expf((float)k * (-4.605170185988091f / 16.0f));
      float sn, cs;
      __sincosf(ang, &sn, &cs);
      rtab[e] = make_float2(cs, sn);
    }
  }
}

// C = A(MxK) * B(NxK)^T, fp16 inputs, BK=64, XOR-swizzled, DOUBLE-BUFFERED LDS.
// MODE 0: 128x64 tile (grid 768 = 64x12), fp32 row-major C
// MODE 1: 128x128 tile (grid 1152 = 18x64). bx<12 (Q,K): fused rms-norm+scale
//         +rope (table) -> fp16 rows [qk][bh][ns][64]; Q additionally scaled
//         by log2(e) so attention works in exp2 domain. bx>=12 (V): fused
//         rms-norm + LDS transpose -> Vout [bh][64][1024] fp16.
template<int MODE>
__global__ __launch_bounds__(256) void gemm_bt(const f16* __restrict__ A,
                                               const f16* __restrict__ B,
                                               float* __restrict__ Cout,
                                               f16* __restrict__ QKout,
                                               f16* __restrict__ Vout,
                                               const int* __restrict__ pos_ids,
                                               const float* __restrict__ q_scale,
                                               const float* __restrict__ k_scale,
                                               const float2* __restrict__ rtab,
                                               int M, int N, int K) {
  constexpr int BN = (MODE == 1) ? 128 : 64;
  constexpr int NJ = BN / 32;
  constexpr int ABUF = 8192;
  constexpr int BBUF = BN*64;
  __shared__ __align__(16) f16 SH[2*ABUF + 2*BBUF];
  const int tid = threadIdx.x;
  const int w = tid >> 6, l = tid & 63;
  const int wr = w >> 1, wc = w & 1;
  const int g = l >> 4, i16 = l & 15;

  int bx, by;
  {
    int id = blockIdx.x;
    const int nbx = (MODE == 1) ? 18 : 12;
    const int chunk = (MODE == 1) ? 144 : 96;
    int idp = (id & 7) * chunk + (id >> 3);
    by = idp / nbx; bx = idp - by * nbx;
  }

  const f32x4 fzero = {0.f, 0.f, 0.f, 0.f};
  f32x4 acc[4][NJ];
#pragma unroll
  for (int i = 0; i < 4; i++)
#pragma unroll
    for (int j = 0; j < NJ; j++) acc[i][j] = fzero;

  const int srow = tid >> 3;
  const int schunk = (tid & 7) ^ (srow & 7);
  const size_t arow = (size_t)(by*128 + srow)*K + schunk*8;
  const size_t brow = (size_t)(bx*BN + srow)*K + schunk*8;

  const int nt = K / 64;  // 12
#define STAGE(buf, k0)                                                          \
  {                                                                             \
    char* AlB = (char*)(SH + (buf)*ABUF) + w*1024;                              \
    char* BlB = (char*)(SH + 2*ABUF + (buf)*BBUF) + w*1024;                     \
    _Pragma("unroll")                                                           \
    for (int n = 0; n < 4; ++n)                                                 \
      gload16(A + arow + (size_t)(n*32)*K + (k0), AlB + n*4096);                \
    _Pragma("unroll")                                                           \
    for (int n = 0; n < BN/32; ++n)                                             \
      gload16(B + brow + (size_t)(n*32)*K + (k0), BlB + n*4096);                \
  }

  STAGE(0, 0);
  __syncthreads();
  for (int t = 0; t < nt; ++t) {
    const int buf = t & 1;
    if (t + 1 < nt) STAGE(buf ^ 1, (t + 1)*64);
    const f16* Ac = SH + buf*ABUF;
    const f16* Bc = SH + 2*ABUF + buf*BBUF;
#pragma unroll
    for (int kk = 0; kk < 2; ++kk) {
      f16x8 af[4], bfr[NJ];
#pragma unroll
      for (int i = 0; i < 4; i++)
        af[i] = *(const f16x8*)(Ac + (wr*64 + i*16 + i16)*64 + ((kk*4 + g) ^ (i16 & 7))*8);
#pragma unroll
      for (int j = 0; j < NJ; j++)
        bfr[j] = *(const f16x8*)(Bc + (wc*(BN/2) + j*16 + i16)*64 + ((kk*4 + g) ^ (i16 & 7))*8);
#pragma unroll
      for (int i = 0; i < 4; i++)
#pragma unroll
        for (int j = 0; j < NJ; j++)
          acc[i][j] = MFMA(af[i], bfr[j], acc[i][j]);
    }
    __syncthreads();
  }
#undef STAGE

  const int m0 = by*128 + wr*64;
  const int n0 = bx*BN + wc*(BN/2);
  if constexpr (MODE == 0) {
#pragma unroll
    for (int i = 0; i < 4; i++)
#pragma unroll
      for (int j = 0; j < NJ; j++)
#pragma unroll
        for (int r = 0; r < 4; r++) {
          int m = m0 + i*16 + g*4 + r;
          int n = n0 + j*16 + i16;
          Cout[(size_t)m*N + n] = acc[i][j][r];
        }
  } else {
  if (bx >= 12) {
    // V: rms-norm + LDS transpose -> Vout [bh][64][1024]
    const int h0 = (bx - 12)*2;
    const int bb = by >> 3;
    const int ns0 = (by & 7) * 128;
    f16* Lt = SH;                       // [128 dh][136]
#pragma unroll
    for (int i = 0; i < 4; i++) {
      f32x4 ssv = fzero;
#pragma unroll
      for (int j = 0; j < 4; j++)
#pragma unroll
        for (int r = 0; r < 4; r++) ssv[r] += acc[i][j][r]*acc[i][j][r];
#pragma unroll
      for (int d = 1; d < 16; d <<= 1)
#pragma unroll
        for (int r = 0; r < 4; r++) ssv[r] += __shfl_xor(ssv[r], d);
#pragma unroll
      for (int r = 0; r < 4; r++) {
        float rinv = rsqrtf(ssv[r] * (1.0f/64.0f) + 1e-6f);
        int nsl = wr*64 + i*16 + g*4 + r;
#pragma unroll
        for (int j = 0; j < 4; j++)
          Lt[(wc*64 + j*16 + i16)*136 + nsl] = (f16)(acc[i][j][r]*rinv);
      }
    }
    __syncthreads();
    const int dh = tid >> 1, half = tid & 1;
    f16* dst = Vout + ((size_t)((bb*NH + h0 + (dh >> 6))*64 + (dh & 63)))*1024
               + ns0 + half*64;
    const f16* ls = Lt + dh*136 + half*64;
#pragma unroll
    for (int e = 0; e < 8; ++e)
      *(uint4*)(dst + e*8) = *(const uint4*)(ls + e*8);
  } else {
    // fused rms-norm + scale + 2D rope (table) for Q/K; Q pre-scaled by log2e
    const int qkv = n0 / DMODEL;
    const int h = (n0 - qkv*DMODEL) >> 6;
    const float* scp = (qkv == 0) ? q_scale : k_scale;
    float scl[4];
#pragma unroll
    for (int j = 0; j < 4; j++) {
      scl[j] = scp[j*16 + i16];
      if (qkv == 0) scl[j] *= 1.4426950408889634f;   // log2(e)
    }
    const float2* rt = rtab + i16;
#pragma unroll
    for (int i = 0; i < 4; i++) {
      f32x4 ssv = fzero;
#pragma unroll
      for (int j = 0; j < 4; j++)
#pragma unroll
        for (int r = 0; r < 4; r++) ssv[r] += acc[i][j][r]*acc[i][j][r];
#pragma unroll
      for (int d = 1; d < 16; d <<= 1)
#pragma unroll
        for (int r = 0; r < 4; r++) ssv[r] += __shfl_xor(ssv[r], d);
#pragma unroll
      for (int r = 0; r < 4; r++) {
        int m = m0 + i*16 + g*4 + r;
        int bb = m >> 10, ns = m & 1023;
        float rinv = rsqrtf(ssv[r] * (1.0f/64.0f) + 1e-6f);
        int2 pp = *(const int2*)(pos_ids + ((size_t)bb*NSEQ + ns)*2);
        float2 t0 = rt[pp.x*16];
        float2 t1 = rt[pp.y*16];
        float x0 = acc[i][0][r]*rinv*scl[0];
        float x1 = acc[i][1][r]*rinv*scl[1];
        float x2 = acc[i][2][r]*rinv*scl[2];
        float x3 = acc[i][3][r]*rinv*scl[3];
        size_t row = ((size_t)qkv*BHN + bb*NH + h)*NSEQ + ns;
        f16* ob = QKout + row*64;
        ob[i16]      = (f16)(x0*t0.x - x1*t0.y);
        ob[16 + i16] = (f16)(x1*t0.x + x0*t0.y);
        ob[32 + i16] = (f16)(x2*t1.x - x3*t1.y);
        ob[48 + i16] = (f16)(x3*t1.x + x2*t1.y);
      }
    }
  }
  }
}

// sigma: LDS K-row p holds physical kv sigma(p); bit layout p={u,b,g,g,c,c} -> {u,g,g,b,c,c}
__device__ __forceinline__ int sigma_perm(int p) {
  return (p & 0x20) | ((p & 0xC) << 1) | ((p & 0x10) >> 2) | (p & 3);
}

#define FM3(a,b,c) fmaxf(fmaxf(a,b),c)

// flash attention: grid (16 qblocks, 96 bh), 4 waves x 16 q rows, KV tile = 64
// exp2-domain softmax (Q pre-scaled by log2e); row-sum l via MFMA(P, ones);
// packed f32->f16 cvt; defer-max THR = 8*log2e.
__global__ __launch_bounds__(256) void attn_kernel(const f16* __restrict__ QKu,
                                                   const f16* __restrict__ Vtu,
                                                   f16* __restrict__ O) {
  const int bh = blockIdx.y;
  const int q0 = blockIdx.x * 64;
  const int tid = threadIdx.x, w = tid >> 6, l = tid & 63;
  const int g = l >> 4, i16 = l & 15;
  const int g4 = g*4;
  const int sw = i16 & 7;
  const int b = bh / NH, h = bh - b*NH;

  __shared__ __align__(16) f16 Ks[2*64*64];
  __shared__ __align__(16) f16 Vs[2*64*64];

  const f16* qrow = QKu + ((size_t)bh*NSEQ + q0 + w*16 + i16)*64;
  f16x8 q0f = *(const f16x8*)(qrow + g*8);
  f16x8 q1f = *(const f16x8*)(qrow + 32 + g*8);

  const char* Kb  = (const char*)(QKu + (size_t)(BHN + bh)*NSEQ*64);
  const char* Vtb = (const char*)(Vtu + (size_t)bh*64*1024);
  const int prow0 = w*8 + (l >> 3);
  const int cl = (l & 7) ^ (l >> 3);
  const char* Ksrc0 = Kb + sigma_perm(prow0)*128 + cl*16;
  const char* Ksrc1 = Kb + (sigma_perm(prow0) + 32)*128 + cl*16;
  const char* Vsrc0 = Vtb + prow0*2048 + cl*16;
  const char* Vsrc1 = Vtb + (prow0 + 32)*2048 + cl*16;

  const f32x4 fzero = {0.f, 0.f, 0.f, 0.f};
  const f16x8 vones = {(f16)1.f,(f16)1.f,(f16)1.f,(f16)1.f,
                       (f16)1.f,(f16)1.f,(f16)1.f,(f16)1.f};
  float mR = -1e30f;
  f32x4 o[4];
  f32x4 acc_l = fzero;
#pragma unroll
  for (int t = 0; t < 4; t++) o[t] = fzero;

  int cur = 0;
  {
    char* kd = (char*)Ks + w*1024;
    char* vd = (char*)Vs + w*1024;
    gload16(Ksrc0, kd);
    gload16(Ksrc1, kd + 4096);
    gload16(Vsrc0, vd);
    gload16(Vsrc1, vd + 4096);
  }
  __syncthreads();

  for (int t = 0; t < 16; ++t) {
    if (t < 15) {
      char* kd = (char*)Ks + (cur^1)*8192 + w*1024;
      char* vd = (char*)Vs + (cur^1)*8192 + w*1024;
      gload16(Ksrc0 + (t+1)*8192, kd);
      gload16(Ksrc1 + (t+1)*8192, kd + 4096);
      gload16(Vsrc0 + (t+1)*128,  vd);
      gload16(Vsrc1 + (t+1)*128,  vd + 4096);
    }
    const f16* Kc = Ks + cur*4096;
    const f16* Vc = Vs + cur*4096;

    f32x4 s[4] = {fzero, fzero, fzero, fzero};
    __builtin_amdgcn_s_setprio(1);
#pragma unroll
    for (int j = 0; j < 4; ++j) {
      const f16* kr = Kc + (j*16 + i16)*64;
      f16x8 k0 = *(const f16x8*)(kr + (g ^ sw)*8);
      f16x8 k1 = *(const f16x8*)(kr + ((g^4) ^ sw)*8);
      s[j] = MFMA(k0, q0f, s[j]);
      s[j] = MFMA(k1, q1f, s[j]);
    }
    __builtin_amdgcn_s_setprio(0);

    // row max (v_max3-friendly triples) + cross-lane reduce over the i16 group
    float t0m = FM3(s[0][0], s[0][1], s[0][2]);
    float t1m = FM3(s[0][3], s[1][0], s[1][1]);
    float t2m = FM3(s[1][2], s[1][3], s[2][0]);
    float t3m = FM3(s[2][1], s[2][2], s[2][3]);
    float t4m = FM3(s[3][0], s[3][1], s[3][2]);
    float tm = fmaxf(FM3(FM3(t0m, t1m, t2m), t3m, t4m), s[3][3]);
    tm = fmaxf(tm, __shfl_xor(tm, 16));
    tm = fmaxf(tm, __shfl_xor(tm, 32));
    if (__any(tm > mR + 11.5416f)) {         // defer-max, THR = 8*log2e
      float nm = fmaxf(mR, tm);
      float fac = __builtin_amdgcn_exp2f(mR - nm);
      mR = nm;
#pragma unroll
      for (int r = 0; r < 4; ++r) {
        float fr = __shfl(fac, g4 + r);
        o[0][r] *= fr; o[1][r] *= fr; o[2][r] *= fr; o[3][r] *= fr;
        acc_l[r] *= fr;
      }
    }
#pragma unroll
    for (int j = 0; j < 4; ++j)
#pragma unroll
      for (int r = 0; r < 4; ++r) s[j][r] = __builtin_amdgcn_exp2f(s[j][r] - mR);

    // packed cvt to the PV A-fragments
    union { h16x2 h[4]; f16x8 v; } u0, u1;
    u0.h[0] = __builtin_amdgcn_cvt_pkrtz(s[0][0], s[0][1]);
    u0.h[1] = __builtin_amdgcn_cvt_pkrtz(s[0][2], s[0][3]);
    u0.h[2] = __builtin_amdgcn_cvt_pkrtz(s[1][0], s[1][1]);
    u0.h[3] = __builtin_amdgcn_cvt_pkrtz(s[1][2], s[1][3]);
    u1.h[0] = __builtin_amdgcn_cvt_pkrtz(s[2][0], s[2][1]);
    u1.h[1] = __builtin_amdgcn_cvt_pkrtz(s[2][2], s[2][3]);
    u1.h[2] = __builtin_amdgcn_cvt_pkrtz(s[3][0], s[3][1]);
    u1.h[3] = __builtin_amdgcn_cvt_pkrtz(s[3][2], s[3][3]);
    f16x8 pa0 = u0.v, pa1 = u1.v;

    __builtin_amdgcn_s_setprio(1);
#pragma unroll
    for (int t2 = 0; t2 < 4; ++t2) {
      const f16* vr = Vc + (t2*16 + i16)*64;
      f16x8 bv0 = *(const f16x8*)(vr + (g ^ sw)*8);
      f16x8 bv1 = *(const f16x8*)(vr + ((g^4) ^ sw)*8);
      o[t2] = MFMA(pa0, bv0, o[t2]);
      o[t2] = MFMA(pa1, bv1, o[t2]);
    }
    acc_l = MFMA(pa0, vones, acc_l);     // row-sum l on the matrix pipe
    acc_l = MFMA(pa1, vones, acc_l);
    __builtin_amdgcn_s_setprio(0);

    __syncthreads();
    cur ^= 1;
  }

#pragma unroll
  for (int r = 0; r < 4; ++r) {
    float invl = 1.0f / acc_l[r];
    int q = q0 + w*16 + g4 + r;
    size_t base = ((size_t)(b*NSEQ + q))*DMODEL + h*DHD;
#pragma unroll
    for (int t2 = 0; t2 < 4; ++t2)
      O[base + t2*16 + i16] = (f16)(o[t2][r] * invl);
  }
}

extern "C" void kernel_launch(void* const* d_in, const int* in_sizes, int n_in,
                              void* d_out, int out_size, void* d_ws, size_t ws_size,
                              hipStream_t stream) {
  const float* hs = (const float*)d_in[0];
  const int*   pos = (const int*)d_in[1];
  const float* Wq = (const float*)d_in[2];
  const float* Wk = (const float*)d_in[3];
  const float* Wv = (const float*)d_in[4];
  const float* Wo = (const float*)d_in[5];
  const float* qs = (const float*)d_in[6];
  const float* ks = (const float*)d_in[7];

  const int nhs = 8192*768;       // 6291456
  const int nw  = 768*768;        // 589824

  char* p = (char*)d_ws;
  f16* Xf   = (f16*)p; p += (size_t)nhs*2;
  f16* Wf   = (f16*)p; p += (size_t)3*nw*2;         // Wq|Wk|Wv
  f16* Wof  = (f16*)p; p += (size_t)nw*2;
  f16* QKpk = (f16*)p; p += (size_t)2*ROWS_PER*64*2;
  f16* Vt   = (f16*)p; p += (size_t)ROWS_PER*64*2;
  f16* Ob   = (f16*)p; p += (size_t)nhs*2;
  float2* Rtab = (float2*)p; p += 512*sizeof(float2);

  cast_kernel<<<nhs/1024, 256, 0, stream>>>(hs, Xf, nhs);
  cast_w_kernel<<<(4*nw)/1024, 256, 0, stream>>>(Wq, Wk, Wv, Wo, Wf, Wof, Rtab, nw);

  gemm_bt<1><<<1152, 256, 0, stream>>>(Xf, Wf, nullptr, QKpk, Vt,
                                       pos, qs, ks, Rtab, 8192, 2304, 768);
  attn_kernel<<<dim3(16, 96), 256, 0, stream>>>(QKpk, Vt, Ob);
  gemm_bt<0><<<768, 256, 0, stream>>>(Ob, Wof, (float*)d_out, nullptr, nullptr,
                                      nullptr, nullptr, nullptr, nullptr, 8192, 768, 768);
}